// Round 1
// baseline (13009.239 us; speedup 1.0000x reference)
//
#include <hip/hip_runtime.h>
#include <math.h>

// ---------------------------------------------------------------------------
// AlexNet forward, batch 128, fp32. Round-0 baseline: fp32 vector ALU kernels.
// Workspace ping-pong: region A (26,615,808 floats) | region B (6,422,528 floats)
// ---------------------------------------------------------------------------

#define A_FLOATS 26615808ull   // y1 [128,64,57,57]
#define B_FLOATS 6422528ull    // p1 [128,64,28,28]

// ---------------- conv1: x[128,3,224,224] -> y1[128,64,57,57], k3 s4 p2, relu
__global__ __launch_bounds__(256) void conv1_kernel(
    const float* __restrict__ x, const float* __restrict__ w,
    const float* __restrict__ bias, float* __restrict__ out) {
  const int b = blockIdx.y;
  const int s = blockIdx.x * 256 + threadIdx.x;
  if (s >= 57 * 57) return;
  const int oh = s / 57, ow = s % 57;
  float iv[27];
#pragma unroll
  for (int ci = 0; ci < 3; ++ci) {
#pragma unroll
    for (int kh = 0; kh < 3; ++kh) {
#pragma unroll
      for (int kw = 0; kw < 3; ++kw) {
        const int ih = oh * 4 - 2 + kh;
        const int iw = ow * 4 - 2 + kw;
        float v = 0.f;
        if (ih >= 0 && ih < 224 && iw >= 0 && iw < 224)
          v = x[(((size_t)b * 3 + ci) * 224 + ih) * 224 + iw];
        iv[ci * 9 + kh * 3 + kw] = v;
      }
    }
  }
  for (int co = 0; co < 64; ++co) {
    float a = bias[co];
#pragma unroll
    for (int p = 0; p < 27; ++p) a = fmaf(w[co * 27 + p], iv[p], a);
    out[((size_t)b * 64 + co) * 3249 + s] = fmaxf(a, 0.f);
  }
}

// ---------------- generic maxpool 3x3 stride 2, VALID (window always in-bounds)
__global__ void maxpool_kernel(const float* __restrict__ in, float* __restrict__ out,
                               int BC, int H, int W, int OH, int OW) {
  const int total = BC * OH * OW;
  for (int idx = blockIdx.x * blockDim.x + threadIdx.x; idx < total;
       idx += gridDim.x * blockDim.x) {
    const int ow = idx % OW;
    int tmp = idx / OW;
    const int oh = tmp % OH;
    const int bc = tmp / OH;
    const float* p = in + (size_t)bc * H * W + (size_t)(oh * 2) * W + ow * 2;
    float m = -INFINITY;
#pragma unroll
    for (int kh = 0; kh < 3; ++kh)
#pragma unroll
      for (int kw = 0; kw < 3; ++kw) m = fmaxf(m, p[kh * W + kw]);
    out[idx] = m;
  }
}

// ---------------- conv2: p1[128,64,28,28] -> y2[128,192,28,28], k5 s1 p2, relu
// block: 256 threads, one image, 16 output channels. LDS: one padded 32x32 in tile.
#define C2_NCO 16
__global__ __launch_bounds__(256) void conv2_kernel(
    const float* __restrict__ in, const float* __restrict__ w,
    const float* __restrict__ bias, float* __restrict__ out) {
  __shared__ float tile[32 * 32];
  const int b = blockIdx.x;
  const int co0 = blockIdx.y * C2_NCO;
  const int t = threadIdx.x;

  int s_[4], oh_[4], ow_[4];
#pragma unroll
  for (int i = 0; i < 4; ++i) {
    const int s = t + i * 256;
    s_[i] = s;
    const int sc = s < 784 ? s : 783;
    oh_[i] = sc / 28;
    ow_[i] = sc % 28;
  }
  float acc[4][C2_NCO];
#pragma unroll
  for (int i = 0; i < 4; ++i)
#pragma unroll
    for (int j = 0; j < C2_NCO; ++j) acc[i][j] = 0.f;

  for (int ci = 0; ci < 64; ++ci) {
    __syncthreads();
    const float* inc = in + ((size_t)b * 64 + ci) * 784;
#pragma unroll
    for (int i = 0; i < 4; ++i) {
      const int idx = t + i * 256;
      const int r = idx >> 5, c = idx & 31;
      const int ir = r - 2, ic = c - 2;
      float v = 0.f;
      if (ir >= 0 && ir < 28 && ic >= 0 && ic < 28) v = inc[ir * 28 + ic];
      tile[idx] = v;
    }
    __syncthreads();
#pragma unroll
    for (int kh = 0; kh < 5; ++kh) {
#pragma unroll
      for (int kw = 0; kw < 5; ++kw) {
        float wv[C2_NCO];
#pragma unroll
        for (int j = 0; j < C2_NCO; ++j)
          wv[j] = w[((size_t)(co0 + j) * 64 + ci) * 25 + kh * 5 + kw];
#pragma unroll
        for (int i = 0; i < 4; ++i) {
          const float v = tile[(oh_[i] + kh) * 32 + ow_[i] + kw];
#pragma unroll
          for (int j = 0; j < C2_NCO; ++j) acc[i][j] = fmaf(wv[j], v, acc[i][j]);
        }
      }
    }
  }
#pragma unroll
  for (int i = 0; i < 4; ++i) {
    if (s_[i] < 784) {
#pragma unroll
      for (int j = 0; j < C2_NCO; ++j) {
        const float r = acc[i][j] + bias[co0 + j];
        out[((size_t)b * 192 + co0 + j) * 784 + s_[i]] = fmaxf(r, 0.f);
      }
    }
  }
}

// ---------------- conv3/4/5: 13x13 spatial, k3 s1 p1, relu. NCO=32.
// blocks cover 256 consecutive (b*169+s) positions; up to 3 images per block.
#define C13_NCO 32
__global__ __launch_bounds__(256) void conv13_kernel(
    const float* __restrict__ in, const float* __restrict__ w,
    const float* __restrict__ bias, float* __restrict__ out, int C_in, int C_out) {
  __shared__ float tile[3 * 240];  // three padded 15x16 tiles
  const int t = threadIdx.x;
  const int g0 = blockIdx.x * 256;
  const int co0 = blockIdx.y * C13_NCO;
  const int bmin = g0 / 169;
  const int g = g0 + t;
  const bool active = g < 128 * 169;
  const int gg = active ? g : 128 * 169 - 1;
  const int b = gg / 169;
  const int s = gg % 169;
  const int oh = s / 13, ow = s % 13;
  const int tbase = (b - bmin) * 240;

  float acc[C13_NCO];
#pragma unroll
  for (int j = 0; j < C13_NCO; ++j) acc[j] = 0.f;

  for (int ci = 0; ci < C_in; ++ci) {
    __syncthreads();
    for (int e = t; e < 3 * 225; e += 256) {
      const int ti = e / 225, idx = e % 225;
      const int r = idx / 15, c = idx % 15;
      const int ir = r - 1, ic = c - 1;
      const int bb = bmin + ti;
      float v = 0.f;
      if (bb < 128 && ir >= 0 && ir < 13 && ic >= 0 && ic < 13)
        v = in[(((size_t)bb * C_in + ci) * 13 + ir) * 13 + ic];
      tile[ti * 240 + r * 16 + c] = v;
    }
    __syncthreads();
    float iv[9];
#pragma unroll
    for (int kh = 0; kh < 3; ++kh)
#pragma unroll
      for (int kw = 0; kw < 3; ++kw)
        iv[kh * 3 + kw] = tile[tbase + (oh + kh) * 16 + (ow + kw)];
    const float* wc = w + (size_t)ci * 9;
#pragma unroll
    for (int j = 0; j < C13_NCO; ++j) {
      const float* wj = wc + (size_t)(co0 + j) * C_in * 9;
#pragma unroll
      for (int p = 0; p < 9; ++p) acc[j] = fmaf(wj[p], iv[p], acc[j]);
    }
  }
  if (active) {
#pragma unroll
    for (int j = 0; j < C13_NCO; ++j) {
      const float r = acc[j] + bias[co0 + j];
      out[((size_t)b * C_out + co0 + j) * 169 + s] = fmaxf(r, 0.f);
    }
  }
}

// ---------------- fc1/fc2: out[M,N] = relu(A[M,K] @ W[N,K]^T + bias)
// BM=64 BN=64 BK=32, 256 threads, 4x4 micro. LDS [k][m]/[k][n] padded to 68.
__global__ __launch_bounds__(256) void fcgemm_kernel(
    const float* __restrict__ A, const float* __restrict__ W,
    const float* __restrict__ bias, float* __restrict__ out,
    int M, int N, int K, int relu) {
  __shared__ float As[32 * 68];
  __shared__ float Ws[32 * 68];
  const int t = threadIdx.x;
  const int tx = t % 16, ty = t / 16;
  const int M0 = blockIdx.x * 64, N0 = blockIdx.y * 64;

  float acc[4][4];
#pragma unroll
  for (int i = 0; i < 4; ++i)
#pragma unroll
    for (int j = 0; j < 4; ++j) acc[i][j] = 0.f;

  for (int k0 = 0; k0 < K; k0 += 32) {
    __syncthreads();
#pragma unroll
    for (int i = 0; i < 8; ++i) {
      const int e = t + i * 256;
      const int kk = e % 32, m = e / 32;
      As[kk * 68 + m] = A[(size_t)(M0 + m) * K + k0 + kk];
    }
#pragma unroll
    for (int i = 0; i < 8; ++i) {
      const int e = t + i * 256;
      const int kk = e % 32, n = e / 32;
      Ws[kk * 68 + n] = W[(size_t)(N0 + n) * K + k0 + kk];
    }
    __syncthreads();
#pragma unroll
    for (int kk = 0; kk < 32; ++kk) {
      const float4 av = *reinterpret_cast<const float4*>(&As[kk * 68 + ty * 4]);
      const float4 wv = *reinterpret_cast<const float4*>(&Ws[kk * 68 + tx * 4]);
      const float a_[4] = {av.x, av.y, av.z, av.w};
      const float w_[4] = {wv.x, wv.y, wv.z, wv.w};
#pragma unroll
      for (int i = 0; i < 4; ++i)
#pragma unroll
        for (int j = 0; j < 4; ++j) acc[i][j] = fmaf(a_[i], w_[j], acc[i][j]);
    }
  }
#pragma unroll
  for (int i = 0; i < 4; ++i) {
    const int m = M0 + ty * 4 + i;
#pragma unroll
    for (int j = 0; j < 4; ++j) {
      const int n = N0 + tx * 4 + j;
      float r = acc[i][j] + bias[n];
      if (relu) r = fmaxf(r, 0.f);
      out[(size_t)m * N + n] = r;
    }
  }
}

// ---------------- fc3: logits[128,10] = h2[128,4096] @ W[10,4096]^T + b
__global__ __launch_bounds__(256) void fc3_kernel(
    const float* __restrict__ A, const float* __restrict__ W,
    const float* __restrict__ bias, float* __restrict__ out) {
  __shared__ float red[256];
  const int b = blockIdx.x;
  const int t = threadIdx.x;
  float acc[10];
#pragma unroll
  for (int n = 0; n < 10; ++n) acc[n] = 0.f;
  const float* a = A + (size_t)b * 4096;
  for (int k = t; k < 4096; k += 256) {
    const float av = a[k];
#pragma unroll
    for (int n = 0; n < 10; ++n) acc[n] = fmaf(av, W[n * 4096 + k], acc[n]);
  }
  for (int n = 0; n < 10; ++n) {
    red[t] = acc[n];
    __syncthreads();
    for (int off = 128; off > 0; off >>= 1) {
      if (t < off) red[t] += red[t + off];
      __syncthreads();
    }
    if (t == 0) out[b * 10 + n] = red[0] + bias[n];
    __syncthreads();
  }
}

// ---------------- post: keep argmax entry, others unif*m, +noise, softmax
__global__ void post_kernel(const float* __restrict__ logits,
                            const float* __restrict__ unif,
                            const float* __restrict__ noise,
                            float* __restrict__ out) {
  const int b = blockIdx.x * blockDim.x + threadIdx.x;
  if (b >= 128) return;
  float lg[10];
#pragma unroll
  for (int j = 0; j < 10; ++j) lg[j] = logits[b * 10 + j];
  float m = lg[0];
  int idx = 0;
#pragma unroll
  for (int j = 1; j < 10; ++j) {
    if (lg[j] > m) { m = lg[j]; idx = j; }  // first max, like torch/jnp
  }
  float v[10];
#pragma unroll
  for (int j = 0; j < 10; ++j)
    v[j] = ((j == idx) ? lg[j] : unif[b * 10 + j] * m) + noise[b * 10 + j];
  float mx = v[0];
#pragma unroll
  for (int j = 1; j < 10; ++j) mx = fmaxf(mx, v[j]);
  float sum = 0.f;
#pragma unroll
  for (int j = 0; j < 10; ++j) { v[j] = expf(v[j] - mx); sum += v[j]; }
  const float inv = 1.f / sum;
#pragma unroll
  for (int j = 0; j < 10; ++j) out[b * 10 + j] = v[j] * inv;
}

// ---------------------------------------------------------------------------
extern "C" void kernel_launch(void* const* d_in, const int* in_sizes, int n_in,
                              void* d_out, int out_size, void* d_ws, size_t ws_size,
                              hipStream_t stream) {
  const float* x     = (const float*)d_in[0];
  const float* w1    = (const float*)d_in[1];
  const float* b1    = (const float*)d_in[2];
  const float* w2    = (const float*)d_in[3];
  const float* b2    = (const float*)d_in[4];
  const float* w3    = (const float*)d_in[5];
  const float* b3    = (const float*)d_in[6];
  const float* w4    = (const float*)d_in[7];
  const float* b4    = (const float*)d_in[8];
  const float* w5    = (const float*)d_in[9];
  const float* b5    = (const float*)d_in[10];
  const float* fc1_w = (const float*)d_in[11];
  const float* fc1_b = (const float*)d_in[12];
  const float* fc2_w = (const float*)d_in[13];
  const float* fc2_b = (const float*)d_in[14];
  const float* fc3_w = (const float*)d_in[15];
  const float* fc3_b = (const float*)d_in[16];
  const float* unif  = (const float*)d_in[17];
  const float* noise = (const float*)d_in[18];
  float* out = (float*)d_out;

  float* A = (float*)d_ws;           // 26,615,808 floats
  float* B = A + A_FLOATS;           //  6,422,528 floats

  // conv1 -> A: [128,64,57,57]
  conv1_kernel<<<dim3(13, 128), 256, 0, stream>>>(x, w1, b1, A);
  // pool1 -> B: [128,64,28,28]
  maxpool_kernel<<<2048, 256, 0, stream>>>(A, B, 128 * 64, 57, 57, 28, 28);
  // conv2 -> A: [128,192,28,28]
  conv2_kernel<<<dim3(128, 192 / C2_NCO), 256, 0, stream>>>(B, w2, b2, A);
  // pool2 -> B: [128,192,13,13]
  maxpool_kernel<<<2048, 256, 0, stream>>>(A, B, 128 * 192, 28, 28, 13, 13);
  // conv3 -> A: [128,384,13,13]
  conv13_kernel<<<dim3(85, 384 / C13_NCO), 256, 0, stream>>>(B, w3, b3, A, 192, 384);
  // conv4 -> B: [128,256,13,13]
  conv13_kernel<<<dim3(85, 256 / C13_NCO), 256, 0, stream>>>(A, w4, b4, B, 384, 256);
  // conv5 -> A: [128,256,13,13]
  conv13_kernel<<<dim3(85, 256 / C13_NCO), 256, 0, stream>>>(B, w5, b5, A, 256, 256);
  // pool3 -> B: [128,256,6,6] == flattened [128,9216]
  maxpool_kernel<<<2048, 256, 0, stream>>>(A, B, 128 * 256, 13, 13, 6, 6);
  // fc1 -> A: [128,4096]
  fcgemm_kernel<<<dim3(2, 64), 256, 0, stream>>>(B, fc1_w, fc1_b, A, 128, 4096, 9216, 1);
  // fc2 -> B: [128,4096]
  fcgemm_kernel<<<dim3(2, 64), 256, 0, stream>>>(A, fc2_w, fc2_b, B, 128, 4096, 4096, 1);
  // fc3 -> A: logits [128,10]
  fc3_kernel<<<128, 256, 0, stream>>>(B, fc3_w, fc3_b, A);
  // post -> d_out: [128,10] softmax
  post_kernel<<<1, 128, 0, stream>>>(A, unif, noise, out);
}

// Round 2
// 4334.763 us; speedup vs baseline: 3.0011x; 3.0011x over previous
//
#include <hip/hip_runtime.h>
#include <math.h>

// ---------------------------------------------------------------------------
// AlexNet forward, batch 128, fp32.
// Round 1: conv2 + conv13 rewritten (LDS-staged weights, reg-blocked, 128-VGPR
// budget via __launch_bounds__(256,4)).
// Workspace ping-pong: region A (26,615,808 floats) | region B (6,422,528 floats)
// ---------------------------------------------------------------------------

#define A_FLOATS 26615808ull   // y1 [128,64,57,57]
#define B_FLOATS 6422528ull    // p1 [128,64,28,28]

// ---------------- conv1: x[128,3,224,224] -> y1[128,64,57,57], k3 s4 p2, relu
__global__ __launch_bounds__(256) void conv1_kernel(
    const float* __restrict__ x, const float* __restrict__ w,
    const float* __restrict__ bias, float* __restrict__ out) {
  const int b = blockIdx.y;
  const int s = blockIdx.x * 256 + threadIdx.x;
  if (s >= 57 * 57) return;
  const int oh = s / 57, ow = s % 57;
  float iv[27];
#pragma unroll
  for (int ci = 0; ci < 3; ++ci) {
#pragma unroll
    for (int kh = 0; kh < 3; ++kh) {
#pragma unroll
      for (int kw = 0; kw < 3; ++kw) {
        const int ih = oh * 4 - 2 + kh;
        const int iw = ow * 4 - 2 + kw;
        float v = 0.f;
        if (ih >= 0 && ih < 224 && iw >= 0 && iw < 224)
          v = x[(((size_t)b * 3 + ci) * 224 + ih) * 224 + iw];
        iv[ci * 9 + kh * 3 + kw] = v;
      }
    }
  }
  for (int co = 0; co < 64; ++co) {
    float a = bias[co];
#pragma unroll
    for (int p = 0; p < 27; ++p) a = fmaf(w[co * 27 + p], iv[p], a);
    out[((size_t)b * 64 + co) * 3249 + s] = fmaxf(a, 0.f);
  }
}

// ---------------- generic maxpool 3x3 stride 2, VALID (window always in-bounds)
__global__ void maxpool_kernel(const float* __restrict__ in, float* __restrict__ out,
                               int BC, int H, int W, int OH, int OW) {
  const int total = BC * OH * OW;
  for (int idx = blockIdx.x * blockDim.x + threadIdx.x; idx < total;
       idx += gridDim.x * blockDim.x) {
    const int ow = idx % OW;
    int tmp = idx / OW;
    const int oh = tmp % OH;
    const int bc = tmp / OH;
    const float* p = in + (size_t)bc * H * W + (size_t)(oh * 2) * W + ow * 2;
    float m = -INFINITY;
#pragma unroll
    for (int kh = 0; kh < 3; ++kh)
#pragma unroll
      for (int kw = 0; kw < 3; ++kw) m = fmaxf(m, p[kh * W + kw]);
    out[idx] = m;
  }
}

// ---------------- conv2: p1[128,64,28,28] -> y2[128,192,28,28], k5 s1 p2, relu
// 256 threads: one image, 16 output channels. Thread t<196 owns 4 horizontally
// consecutive outputs (row t/7, cols 4*(t%7)..+3). Weights in LDS [p][co].
#define C2_NCO 16
__global__ __launch_bounds__(256, 4) void conv2_kernel(
    const float* __restrict__ in, const float* __restrict__ w,
    const float* __restrict__ bias, float* __restrict__ out) {
  __shared__ float tile[32 * 32];          // padded input tile (rows/cols -2..29)
  __shared__ float wlds[25 * C2_NCO];      // weights for current ci, [p][co]
  const int b = blockIdx.x;
  const int co0 = blockIdx.y * C2_NCO;
  const int t = threadIdx.x;
  const bool act = t < 196;
  const int tc = act ? t : 0;
  const int oh = tc / 7;
  const int ow0 = (tc % 7) * 4;

  float acc[4][C2_NCO];
#pragma unroll
  for (int i = 0; i < 4; ++i)
#pragma unroll
    for (int j = 0; j < C2_NCO; ++j) acc[i][j] = 0.f;

  for (int ci = 0; ci < 64; ++ci) {
    __syncthreads();
    const float* inc = in + ((size_t)b * 64 + ci) * 784;
#pragma unroll
    for (int i = 0; i < 4; ++i) {
      const int idx = t + i * 256;
      const int r = idx >> 5, c = idx & 31;
      const int ir = r - 2, ic = c - 2;
      float v = 0.f;
      if (ir >= 0 && ir < 28 && ic >= 0 && ic < 28) v = inc[ir * 28 + ic];
      tile[idx] = v;
    }
    for (int e = t; e < 25 * C2_NCO; e += 256) {
      const int p = e >> 4, j = e & 15;
      wlds[e] = w[(size_t)(co0 + j) * 1600 + ci * 25 + p];
    }
    __syncthreads();
    if (act) {
#pragma unroll
      for (int kh = 0; kh < 5; ++kh) {
        const float4 vlo = *reinterpret_cast<const float4*>(&tile[(oh + kh) * 32 + ow0]);
        const float4 vhi = *reinterpret_cast<const float4*>(&tile[(oh + kh) * 32 + ow0 + 4]);
        const float v[8] = {vlo.x, vlo.y, vlo.z, vlo.w, vhi.x, vhi.y, vhi.z, vhi.w};
#pragma unroll
        for (int kw = 0; kw < 5; ++kw) {
          const int p = kh * 5 + kw;
          const float4 w0 = *reinterpret_cast<const float4*>(&wlds[p * 16 + 0]);
          const float4 w1 = *reinterpret_cast<const float4*>(&wlds[p * 16 + 4]);
          const float4 w2 = *reinterpret_cast<const float4*>(&wlds[p * 16 + 8]);
          const float4 w3 = *reinterpret_cast<const float4*>(&wlds[p * 16 + 12]);
          const float wr[16] = {w0.x, w0.y, w0.z, w0.w, w1.x, w1.y, w1.z, w1.w,
                                w2.x, w2.y, w2.z, w2.w, w3.x, w3.y, w3.z, w3.w};
#pragma unroll
          for (int i = 0; i < 4; ++i)
#pragma unroll
            for (int j = 0; j < C2_NCO; ++j)
              acc[i][j] = fmaf(wr[j], v[kw + i], acc[i][j]);
        }
      }
    }
  }
  if (act) {
    const int obase = oh * 28 + ow0;
#pragma unroll
    for (int j = 0; j < C2_NCO; ++j) {
      const float bj = bias[co0 + j];
      float4 r;
      r.x = fmaxf(acc[0][j] + bj, 0.f);
      r.y = fmaxf(acc[1][j] + bj, 0.f);
      r.z = fmaxf(acc[2][j] + bj, 0.f);
      r.w = fmaxf(acc[3][j] + bj, 0.f);
      *reinterpret_cast<float4*>(&out[((size_t)b * 192 + co0 + j) * 784 + obase]) = r;
    }
  }
}

// ---------------- conv3/4/5: 13x13 spatial, k3 s1 p1, relu.
// Block = 3 images (507 positions), 2 positions/thread, 32 output channels.
// Weights in LDS [p][co]; input tiles padded 15x16.
__global__ __launch_bounds__(256, 4) void conv13_kernel(
    const float* __restrict__ in, const float* __restrict__ w,
    const float* __restrict__ bias, float* __restrict__ out, int C_in, int C_out) {
  __shared__ float tile[3 * 240];   // three padded 15x16 tiles
  __shared__ float wlds[9 * 32];
  const int t = threadIdx.x;
  const int bmin = blockIdx.x * 3;
  const int g0 = bmin * 169;
  const int co0 = blockIdx.y * 32;
  const int P = 128 * 169;

  const int ga = g0 + t;
  const int gb = g0 + 256 + t;
  const bool acta = ga < P;                 // t < 256 < 507 always
  const bool actb = (t < 251) && (gb < P);  // positions 256..506 of this block
  const int gca = acta ? ga : P - 1;
  const int gcb = actb ? gb : P - 1;
  const int b0 = gca / 169, s0 = gca % 169;
  const int b1 = gcb / 169, s1 = gcb % 169;
  const int base0 = (b0 - bmin < 0 ? 0 : (b0 - bmin > 2 ? 2 : b0 - bmin)) * 240
                    + (s0 / 13) * 16 + (s0 % 13);
  const int base1 = (b1 - bmin < 0 ? 0 : (b1 - bmin > 2 ? 2 : b1 - bmin)) * 240
                    + (s1 / 13) * 16 + (s1 % 13);

  float acc0[32], acc1[32];
#pragma unroll
  for (int j = 0; j < 32; ++j) { acc0[j] = 0.f; acc1[j] = 0.f; }

  for (int ci = 0; ci < C_in; ++ci) {
    __syncthreads();
    for (int e = t; e < 3 * 225; e += 256) {
      const int ti = e / 225, idx = e % 225;
      const int r = idx / 15, c = idx % 15;
      const int bb = bmin + ti;
      const int ir = r - 1, ic = c - 1;
      float v = 0.f;
      if (bb < 128 && ir >= 0 && ir < 13 && ic >= 0 && ic < 13)
        v = in[(((size_t)bb * C_in + ci) * 13 + ir) * 13 + ic];
      tile[ti * 240 + r * 16 + c] = v;
    }
    for (int e = t; e < 9 * 32; e += 256) {
      const int p = e >> 5, j = e & 31;
      wlds[e] = w[(size_t)(co0 + j) * C_in * 9 + ci * 9 + p];
    }
    __syncthreads();
#pragma unroll
    for (int p = 0; p < 9; ++p) {
      const int kh = p / 3, kw = p % 3;
      const float ia = tile[base0 + kh * 16 + kw];
      const float ib = tile[base1 + kh * 16 + kw];
#pragma unroll
      for (int h = 0; h < 2; ++h) {
        const float4 w0 = *reinterpret_cast<const float4*>(&wlds[p * 32 + h * 16 + 0]);
        const float4 w1 = *reinterpret_cast<const float4*>(&wlds[p * 32 + h * 16 + 4]);
        const float4 w2 = *reinterpret_cast<const float4*>(&wlds[p * 32 + h * 16 + 8]);
        const float4 w3 = *reinterpret_cast<const float4*>(&wlds[p * 32 + h * 16 + 12]);
        const float wr[16] = {w0.x, w0.y, w0.z, w0.w, w1.x, w1.y, w1.z, w1.w,
                              w2.x, w2.y, w2.z, w2.w, w3.x, w3.y, w3.z, w3.w};
#pragma unroll
        for (int j = 0; j < 16; ++j) {
          acc0[h * 16 + j] = fmaf(wr[j], ia, acc0[h * 16 + j]);
          acc1[h * 16 + j] = fmaf(wr[j], ib, acc1[h * 16 + j]);
        }
      }
    }
  }
  if (acta) {
#pragma unroll
    for (int j = 0; j < 32; ++j)
      out[((size_t)b0 * C_out + co0 + j) * 169 + s0] =
          fmaxf(acc0[j] + bias[co0 + j], 0.f);
  }
  if (actb) {
#pragma unroll
    for (int j = 0; j < 32; ++j)
      out[((size_t)b1 * C_out + co0 + j) * 169 + s1] =
          fmaxf(acc1[j] + bias[co0 + j], 0.f);
  }
}

// ---------------- fc1/fc2: out[M,N] = relu(A[M,K] @ W[N,K]^T + bias)
// BM=64 BN=64 BK=32, 256 threads, 4x4 micro. LDS [k][m]/[k][n] padded to 68.
__global__ __launch_bounds__(256) void fcgemm_kernel(
    const float* __restrict__ A, const float* __restrict__ W,
    const float* __restrict__ bias, float* __restrict__ out,
    int M, int N, int K, int relu) {
  __shared__ float As[32 * 68];
  __shared__ float Ws[32 * 68];
  const int t = threadIdx.x;
  const int tx = t % 16, ty = t / 16;
  const int M0 = blockIdx.x * 64, N0 = blockIdx.y * 64;

  float acc[4][4];
#pragma unroll
  for (int i = 0; i < 4; ++i)
#pragma unroll
    for (int j = 0; j < 4; ++j) acc[i][j] = 0.f;

  for (int k0 = 0; k0 < K; k0 += 32) {
    __syncthreads();
#pragma unroll
    for (int i = 0; i < 8; ++i) {
      const int e = t + i * 256;
      const int kk = e % 32, m = e / 32;
      As[kk * 68 + m] = A[(size_t)(M0 + m) * K + k0 + kk];
    }
#pragma unroll
    for (int i = 0; i < 8; ++i) {
      const int e = t + i * 256;
      const int kk = e % 32, n = e / 32;
      Ws[kk * 68 + n] = W[(size_t)(N0 + n) * K + k0 + kk];
    }
    __syncthreads();
#pragma unroll
    for (int kk = 0; kk < 32; ++kk) {
      const float4 av = *reinterpret_cast<const float4*>(&As[kk * 68 + ty * 4]);
      const float4 wv = *reinterpret_cast<const float4*>(&Ws[kk * 68 + tx * 4]);
      const float a_[4] = {av.x, av.y, av.z, av.w};
      const float w_[4] = {wv.x, wv.y, wv.z, wv.w};
#pragma unroll
      for (int i = 0; i < 4; ++i)
#pragma unroll
        for (int j = 0; j < 4; ++j) acc[i][j] = fmaf(a_[i], w_[j], acc[i][j]);
    }
  }
#pragma unroll
  for (int i = 0; i < 4; ++i) {
    const int m = M0 + ty * 4 + i;
#pragma unroll
    for (int j = 0; j < 4; ++j) {
      const int n = N0 + tx * 4 + j;
      float r = acc[i][j] + bias[n];
      if (relu) r = fmaxf(r, 0.f);
      out[(size_t)m * N + n] = r;
    }
  }
}

// ---------------- fc3: logits[128,10] = h2[128,4096] @ W[10,4096]^T + b
__global__ __launch_bounds__(256) void fc3_kernel(
    const float* __restrict__ A, const float* __restrict__ W,
    const float* __restrict__ bias, float* __restrict__ out) {
  __shared__ float red[256];
  const int b = blockIdx.x;
  const int t = threadIdx.x;
  float acc[10];
#pragma unroll
  for (int n = 0; n < 10; ++n) acc[n] = 0.f;
  const float* a = A + (size_t)b * 4096;
  for (int k = t; k < 4096; k += 256) {
    const float av = a[k];
#pragma unroll
    for (int n = 0; n < 10; ++n) acc[n] = fmaf(av, W[n * 4096 + k], acc[n]);
  }
  for (int n = 0; n < 10; ++n) {
    red[t] = acc[n];
    __syncthreads();
    for (int off = 128; off > 0; off >>= 1) {
      if (t < off) red[t] += red[t + off];
      __syncthreads();
    }
    if (t == 0) out[b * 10 + n] = red[0] + bias[n];
    __syncthreads();
  }
}

// ---------------- post: keep argmax entry, others unif*m, +noise, softmax
__global__ void post_kernel(const float* __restrict__ logits,
                            const float* __restrict__ unif,
                            const float* __restrict__ noise,
                            float* __restrict__ out) {
  const int b = blockIdx.x * blockDim.x + threadIdx.x;
  if (b >= 128) return;
  float lg[10];
#pragma unroll
  for (int j = 0; j < 10; ++j) lg[j] = logits[b * 10 + j];
  float m = lg[0];
  int idx = 0;
#pragma unroll
  for (int j = 1; j < 10; ++j) {
    if (lg[j] > m) { m = lg[j]; idx = j; }  // first max, like torch/jnp
  }
  float v[10];
#pragma unroll
  for (int j = 0; j < 10; ++j)
    v[j] = ((j == idx) ? lg[j] : unif[b * 10 + j] * m) + noise[b * 10 + j];
  float mx = v[0];
#pragma unroll
  for (int j = 1; j < 10; ++j) mx = fmaxf(mx, v[j]);
  float sum = 0.f;
#pragma unroll
  for (int j = 0; j < 10; ++j) { v[j] = expf(v[j] - mx); sum += v[j]; }
  const float inv = 1.f / sum;
#pragma unroll
  for (int j = 0; j < 10; ++j) out[b * 10 + j] = v[j] * inv;
}

// ---------------------------------------------------------------------------
extern "C" void kernel_launch(void* const* d_in, const int* in_sizes, int n_in,
                              void* d_out, int out_size, void* d_ws, size_t ws_size,
                              hipStream_t stream) {
  const float* x     = (const float*)d_in[0];
  const float* w1    = (const float*)d_in[1];
  const float* b1    = (const float*)d_in[2];
  const float* w2    = (const float*)d_in[3];
  const float* b2    = (const float*)d_in[4];
  const float* w3    = (const float*)d_in[5];
  const float* b3    = (const float*)d_in[6];
  const float* w4    = (const float*)d_in[7];
  const float* b4    = (const float*)d_in[8];
  const float* w5    = (const float*)d_in[9];
  const float* b5    = (const float*)d_in[10];
  const float* fc1_w = (const float*)d_in[11];
  const float* fc1_b = (const float*)d_in[12];
  const float* fc2_w = (const float*)d_in[13];
  const float* fc2_b = (const float*)d_in[14];
  const float* fc3_w = (const float*)d_in[15];
  const float* fc3_b = (const float*)d_in[16];
  const float* unif  = (const float*)d_in[17];
  const float* noise = (const float*)d_in[18];
  float* out = (float*)d_out;

  float* A = (float*)d_ws;           // 26,615,808 floats
  float* B = A + A_FLOATS;           //  6,422,528 floats

  // conv1 -> A: [128,64,57,57]
  conv1_kernel<<<dim3(13, 128), 256, 0, stream>>>(x, w1, b1, A);
  // pool1 -> B: [128,64,28,28]
  maxpool_kernel<<<2048, 256, 0, stream>>>(A, B, 128 * 64, 57, 57, 28, 28);
  // conv2 -> A: [128,192,28,28]
  conv2_kernel<<<dim3(128, 192 / C2_NCO), 256, 0, stream>>>(B, w2, b2, A);
  // pool2 -> B: [128,192,13,13]
  maxpool_kernel<<<2048, 256, 0, stream>>>(A, B, 128 * 192, 28, 28, 13, 13);
  // conv3 -> A: [128,384,13,13]
  conv13_kernel<<<dim3(43, 384 / 32), 256, 0, stream>>>(B, w3, b3, A, 192, 384);
  // conv4 -> B: [128,256,13,13]
  conv13_kernel<<<dim3(43, 256 / 32), 256, 0, stream>>>(A, w4, b4, B, 384, 256);
  // conv5 -> A: [128,256,13,13]
  conv13_kernel<<<dim3(43, 256 / 32), 256, 0, stream>>>(B, w5, b5, A, 256, 256);
  // pool3 -> B: [128,256,6,6] == flattened [128,9216]
  maxpool_kernel<<<2048, 256, 0, stream>>>(A, B, 128 * 256, 13, 13, 6, 6);
  // fc1 -> A: [128,4096]
  fcgemm_kernel<<<dim3(2, 64), 256, 0, stream>>>(B, fc1_w, fc1_b, A, 128, 4096, 9216, 1);
  // fc2 -> B: [128,4096]
  fcgemm_kernel<<<dim3(2, 64), 256, 0, stream>>>(A, fc2_w, fc2_b, B, 128, 4096, 4096, 1);
  // fc3 -> A: logits [128,10]
  fc3_kernel<<<128, 256, 0, stream>>>(B, fc3_w, fc3_b, A);
  // post -> d_out: [128,10] softmax
  post_kernel<<<1, 128, 0, stream>>>(A, unif, noise, out);
}

// Round 3
// 3780.817 us; speedup vs baseline: 3.4409x; 1.1465x over previous
//
#include <hip/hip_runtime.h>
#include <math.h>

// ---------------------------------------------------------------------------
// AlexNet forward, batch 128, fp32.
// Round 2: conv13 rewritten — 1 position/thread, weights pre-transposed to
// [ci*9+p][co] and read via the scalar pipe (uniform s_load), inputs in LDS.
// Workspace: region A (26,615,808 floats) | region B (6,422,528 floats)
//            region C = A + 20,000,000 (transposed conv3/4/5 weights, 2.14M)
// ---------------------------------------------------------------------------

#define A_FLOATS 26615808ull   // y1 [128,64,57,57]
#define B_FLOATS 6422528ull    // p1 [128,64,28,28]

// ---------------- conv1: x[128,3,224,224] -> y1[128,64,57,57], k3 s4 p2, relu
__global__ __launch_bounds__(256) void conv1_kernel(
    const float* __restrict__ x, const float* __restrict__ w,
    const float* __restrict__ bias, float* __restrict__ out) {
  const int b = blockIdx.y;
  const int s = blockIdx.x * 256 + threadIdx.x;
  if (s >= 57 * 57) return;
  const int oh = s / 57, ow = s % 57;
  float iv[27];
#pragma unroll
  for (int ci = 0; ci < 3; ++ci) {
#pragma unroll
    for (int kh = 0; kh < 3; ++kh) {
#pragma unroll
      for (int kw = 0; kw < 3; ++kw) {
        const int ih = oh * 4 - 2 + kh;
        const int iw = ow * 4 - 2 + kw;
        float v = 0.f;
        if (ih >= 0 && ih < 224 && iw >= 0 && iw < 224)
          v = x[(((size_t)b * 3 + ci) * 224 + ih) * 224 + iw];
        iv[ci * 9 + kh * 3 + kw] = v;
      }
    }
  }
  for (int co = 0; co < 64; ++co) {
    float a = bias[co];
#pragma unroll
    for (int p = 0; p < 27; ++p) a = fmaf(w[co * 27 + p], iv[p], a);
    out[((size_t)b * 64 + co) * 3249 + s] = fmaxf(a, 0.f);
  }
}

// ---------------- generic maxpool 3x3 stride 2, VALID (window always in-bounds)
__global__ void maxpool_kernel(const float* __restrict__ in, float* __restrict__ out,
                               int BC, int H, int W, int OH, int OW) {
  const int total = BC * OH * OW;
  for (int idx = blockIdx.x * blockDim.x + threadIdx.x; idx < total;
       idx += gridDim.x * blockDim.x) {
    const int ow = idx % OW;
    int tmp = idx / OW;
    const int oh = tmp % OH;
    const int bc = tmp / OH;
    const float* p = in + (size_t)bc * H * W + (size_t)(oh * 2) * W + ow * 2;
    float m = -INFINITY;
#pragma unroll
    for (int kh = 0; kh < 3; ++kh)
#pragma unroll
      for (int kw = 0; kw < 3; ++kw) m = fmaxf(m, p[kh * W + kw]);
    out[idx] = m;
  }
}

// ---------------- conv2: p1[128,64,28,28] -> y2[128,192,28,28], k5 s1 p2, relu
// 256 threads: one image, 16 output channels. Thread t<196 owns 4 horizontally
// consecutive outputs (row t/7, cols 4*(t%7)..+3). Weights in LDS [p][co].
#define C2_NCO 16
__global__ __launch_bounds__(256, 4) void conv2_kernel(
    const float* __restrict__ in, const float* __restrict__ w,
    const float* __restrict__ bias, float* __restrict__ out) {
  __shared__ float tile[32 * 32];          // padded input tile (rows/cols -2..29)
  __shared__ float wlds[25 * C2_NCO];      // weights for current ci, [p][co]
  const int b = blockIdx.x;
  const int co0 = blockIdx.y * C2_NCO;
  const int t = threadIdx.x;
  const bool act = t < 196;
  const int tc = act ? t : 0;
  const int oh = tc / 7;
  const int ow0 = (tc % 7) * 4;

  float acc[4][C2_NCO];
#pragma unroll
  for (int i = 0; i < 4; ++i)
#pragma unroll
    for (int j = 0; j < C2_NCO; ++j) acc[i][j] = 0.f;

  for (int ci = 0; ci < 64; ++ci) {
    __syncthreads();
    const float* inc = in + ((size_t)b * 64 + ci) * 784;
#pragma unroll
    for (int i = 0; i < 4; ++i) {
      const int idx = t + i * 256;
      const int r = idx >> 5, c = idx & 31;
      const int ir = r - 2, ic = c - 2;
      float v = 0.f;
      if (ir >= 0 && ir < 28 && ic >= 0 && ic < 28) v = inc[ir * 28 + ic];
      tile[idx] = v;
    }
    for (int e = t; e < 25 * C2_NCO; e += 256) {
      const int p = e >> 4, j = e & 15;
      wlds[e] = w[(size_t)(co0 + j) * 1600 + ci * 25 + p];
    }
    __syncthreads();
    if (act) {
#pragma unroll
      for (int kh = 0; kh < 5; ++kh) {
        const float4 vlo = *reinterpret_cast<const float4*>(&tile[(oh + kh) * 32 + ow0]);
        const float4 vhi = *reinterpret_cast<const float4*>(&tile[(oh + kh) * 32 + ow0 + 4]);
        const float v[8] = {vlo.x, vlo.y, vlo.z, vlo.w, vhi.x, vhi.y, vhi.z, vhi.w};
#pragma unroll
        for (int kw = 0; kw < 5; ++kw) {
          const int p = kh * 5 + kw;
          const float4 w0 = *reinterpret_cast<const float4*>(&wlds[p * 16 + 0]);
          const float4 w1 = *reinterpret_cast<const float4*>(&wlds[p * 16 + 4]);
          const float4 w2 = *reinterpret_cast<const float4*>(&wlds[p * 16 + 8]);
          const float4 w3 = *reinterpret_cast<const float4*>(&wlds[p * 16 + 12]);
          const float wr[16] = {w0.x, w0.y, w0.z, w0.w, w1.x, w1.y, w1.z, w1.w,
                                w2.x, w2.y, w2.z, w2.w, w3.x, w3.y, w3.z, w3.w};
#pragma unroll
          for (int i = 0; i < 4; ++i)
#pragma unroll
            for (int j = 0; j < C2_NCO; ++j)
              acc[i][j] = fmaf(wr[j], v[kw + i], acc[i][j]);
        }
      }
    }
  }
  if (act) {
    const int obase = oh * 28 + ow0;
#pragma unroll
    for (int j = 0; j < C2_NCO; ++j) {
      const float bj = bias[co0 + j];
      float4 r;
      r.x = fmaxf(acc[0][j] + bj, 0.f);
      r.y = fmaxf(acc[1][j] + bj, 0.f);
      r.z = fmaxf(acc[2][j] + bj, 0.f);
      r.w = fmaxf(acc[3][j] + bj, 0.f);
      *reinterpret_cast<float4*>(&out[((size_t)b * 192 + co0 + j) * 784 + obase]) = r;
    }
  }
}

// ---------------- weight transpose for conv3/4/5: w[co][ci][p] -> wt[ci*9+p][co]
__global__ void wtrans_kernel(const float* __restrict__ w, float* __restrict__ wt,
                              int C_in, int C_out) {
  const int total = C_out * C_in * 9;
  for (int e = blockIdx.x * blockDim.x + threadIdx.x; e < total;
       e += gridDim.x * blockDim.x) {
    const int co = e % C_out;
    const int rp = e / C_out;  // ci*9+p
    wt[e] = w[(size_t)co * C_in * 9 + rp];
  }
}

// ---------------- conv3/4/5: 13x13 spatial, k3 s1 p1, relu.
// 1 output position per thread, 32 output channels. Weights from wt (uniform
// consecutive -> scalar loads). Input tiles (up to 3 images) in LDS, padded 15x16.
__global__ __launch_bounds__(256, 4) void conv13_kernel(
    const float* __restrict__ in, const float* __restrict__ wt,
    const float* __restrict__ bias, float* __restrict__ out, int C_in, int C_out) {
  __shared__ float tile[3 * 240];
  const int t = threadIdx.x;
  const int g0 = blockIdx.x * 256;
  const int co0 = blockIdx.y * 32;
  const int bmin = g0 / 169;
  const int P = 128 * 169;
  const int g = g0 + t;
  const bool active = g < P;
  const int gc = active ? g : P - 1;
  const int b = gc / 169, s = gc % 169;
  const int base = (b - bmin) * 240 + (s / 13) * 16 + (s % 13);

  float acc[32];
#pragma unroll
  for (int j = 0; j < 32; ++j) acc[j] = 0.f;

  for (int ci = 0; ci < C_in; ++ci) {
    __syncthreads();
    for (int e = t; e < 675; e += 256) {
      const int ti = e / 225, idx = e % 225;
      const int r = idx / 15, c = idx % 15;
      const int bb = bmin + ti;
      const int ir = r - 1, ic = c - 1;
      float v = 0.f;
      if (bb < 128 && ir >= 0 && ir < 13 && ic >= 0 && ic < 13)
        v = in[(((size_t)bb * C_in + ci) * 13 + ir) * 13 + ic];
      tile[ti * 240 + r * 16 + c] = v;
    }
    __syncthreads();
    const float* wc = wt + (size_t)ci * 9 * C_out + co0;
#pragma unroll
    for (int p = 0; p < 9; ++p) {
      const float v = tile[base + (p / 3) * 16 + (p % 3)];
      const float* wp = wc + p * C_out;  // uniform, consecutive -> s_load
#pragma unroll
      for (int j = 0; j < 32; ++j) acc[j] = fmaf(wp[j], v, acc[j]);
    }
  }
  if (active) {
#pragma unroll
    for (int j = 0; j < 32; ++j)
      out[((size_t)b * C_out + co0 + j) * 169 + s] =
          fmaxf(acc[j] + bias[co0 + j], 0.f);
  }
}

// ---------------- fc1/fc2: out[M,N] = relu(A[M,K] @ W[N,K]^T + bias)
// BM=64 BN=64 BK=32, 256 threads, 4x4 micro. LDS [k][m]/[k][n] padded to 68.
__global__ __launch_bounds__(256) void fcgemm_kernel(
    const float* __restrict__ A, const float* __restrict__ W,
    const float* __restrict__ bias, float* __restrict__ out,
    int M, int N, int K, int relu) {
  __shared__ float As[32 * 68];
  __shared__ float Ws[32 * 68];
  const int t = threadIdx.x;
  const int tx = t % 16, ty = t / 16;
  const int M0 = blockIdx.x * 64, N0 = blockIdx.y * 64;

  float acc[4][4];
#pragma unroll
  for (int i = 0; i < 4; ++i)
#pragma unroll
    for (int j = 0; j < 4; ++j) acc[i][j] = 0.f;

  for (int k0 = 0; k0 < K; k0 += 32) {
    __syncthreads();
#pragma unroll
    for (int i = 0; i < 8; ++i) {
      const int e = t + i * 256;
      const int kk = e % 32, m = e / 32;
      As[kk * 68 + m] = A[(size_t)(M0 + m) * K + k0 + kk];
    }
#pragma unroll
    for (int i = 0; i < 8; ++i) {
      const int e = t + i * 256;
      const int kk = e % 32, n = e / 32;
      Ws[kk * 68 + n] = W[(size_t)(N0 + n) * K + k0 + kk];
    }
    __syncthreads();
#pragma unroll
    for (int kk = 0; kk < 32; ++kk) {
      const float4 av = *reinterpret_cast<const float4*>(&As[kk * 68 + ty * 4]);
      const float4 wv = *reinterpret_cast<const float4*>(&Ws[kk * 68 + tx * 4]);
      const float a_[4] = {av.x, av.y, av.z, av.w};
      const float w_[4] = {wv.x, wv.y, wv.z, wv.w};
#pragma unroll
      for (int i = 0; i < 4; ++i)
#pragma unroll
        for (int j = 0; j < 4; ++j) acc[i][j] = fmaf(a_[i], w_[j], acc[i][j]);
    }
  }
#pragma unroll
  for (int i = 0; i < 4; ++i) {
    const int m = M0 + ty * 4 + i;
#pragma unroll
    for (int j = 0; j < 4; ++j) {
      const int n = N0 + tx * 4 + j;
      float r = acc[i][j] + bias[n];
      if (relu) r = fmaxf(r, 0.f);
      out[(size_t)m * N + n] = r;
    }
  }
}

// ---------------- fc3: logits[128,10] = h2[128,4096] @ W[10,4096]^T + b
__global__ __launch_bounds__(256) void fc3_kernel(
    const float* __restrict__ A, const float* __restrict__ W,
    const float* __restrict__ bias, float* __restrict__ out) {
  __shared__ float red[256];
  const int b = blockIdx.x;
  const int t = threadIdx.x;
  float acc[10];
#pragma unroll
  for (int n = 0; n < 10; ++n) acc[n] = 0.f;
  const float* a = A + (size_t)b * 4096;
  for (int k = t; k < 4096; k += 256) {
    const float av = a[k];
#pragma unroll
    for (int n = 0; n < 10; ++n) acc[n] = fmaf(av, W[n * 4096 + k], acc[n]);
  }
  for (int n = 0; n < 10; ++n) {
    red[t] = acc[n];
    __syncthreads();
    for (int off = 128; off > 0; off >>= 1) {
      if (t < off) red[t] += red[t + off];
      __syncthreads();
    }
    if (t == 0) out[b * 10 + n] = red[0] + bias[n];
    __syncthreads();
  }
}

// ---------------- post: keep argmax entry, others unif*m, +noise, softmax
__global__ void post_kernel(const float* __restrict__ logits,
                            const float* __restrict__ unif,
                            const float* __restrict__ noise,
                            float* __restrict__ out) {
  const int b = blockIdx.x * blockDim.x + threadIdx.x;
  if (b >= 128) return;
  float lg[10];
#pragma unroll
  for (int j = 0; j < 10; ++j) lg[j] = logits[b * 10 + j];
  float m = lg[0];
  int idx = 0;
#pragma unroll
  for (int j = 1; j < 10; ++j) {
    if (lg[j] > m) { m = lg[j]; idx = j; }  // first max, like torch/jnp
  }
  float v[10];
#pragma unroll
  for (int j = 0; j < 10; ++j)
    v[j] = ((j == idx) ? lg[j] : unif[b * 10 + j] * m) + noise[b * 10 + j];
  float mx = v[0];
#pragma unroll
  for (int j = 1; j < 10; ++j) mx = fmaxf(mx, v[j]);
  float sum = 0.f;
#pragma unroll
  for (int j = 0; j < 10; ++j) { v[j] = expf(v[j] - mx); sum += v[j]; }
  const float inv = 1.f / sum;
#pragma unroll
  for (int j = 0; j < 10; ++j) out[b * 10 + j] = v[j] * inv;
}

// ---------------------------------------------------------------------------
extern "C" void kernel_launch(void* const* d_in, const int* in_sizes, int n_in,
                              void* d_out, int out_size, void* d_ws, size_t ws_size,
                              hipStream_t stream) {
  const float* x     = (const float*)d_in[0];
  const float* w1    = (const float*)d_in[1];
  const float* b1    = (const float*)d_in[2];
  const float* w2    = (const float*)d_in[3];
  const float* b2    = (const float*)d_in[4];
  const float* w3    = (const float*)d_in[5];
  const float* b3    = (const float*)d_in[6];
  const float* w4    = (const float*)d_in[7];
  const float* b4    = (const float*)d_in[8];
  const float* w5    = (const float*)d_in[9];
  const float* b5    = (const float*)d_in[10];
  const float* fc1_w = (const float*)d_in[11];
  const float* fc1_b = (const float*)d_in[12];
  const float* fc2_w = (const float*)d_in[13];
  const float* fc2_b = (const float*)d_in[14];
  const float* fc3_w = (const float*)d_in[15];
  const float* fc3_b = (const float*)d_in[16];
  const float* unif  = (const float*)d_in[17];
  const float* noise = (const float*)d_in[18];
  float* out = (float*)d_out;

  float* A = (float*)d_ws;           // 26,615,808 floats
  float* B = A + A_FLOATS;           //  6,422,528 floats
  // region C: transposed conv weights, placed in dead tail of A
  // (conv2 output uses only 19.27M floats of A; conv3/5 outputs even less)
  float* wt3 = A + 20000000;         // 192*9*384 = 663,552
  float* wt4 = wt3 + 663552;         // 384*9*256 = 884,736
  float* wt5 = wt4 + 884736;         // 256*9*256 = 589,824  (ends at 22,138,112 < A_FLOATS)

  // conv1 -> A: [128,64,57,57]
  conv1_kernel<<<dim3(13, 128), 256, 0, stream>>>(x, w1, b1, A);
  // pool1 -> B: [128,64,28,28]
  maxpool_kernel<<<2048, 256, 0, stream>>>(A, B, 128 * 64, 57, 57, 28, 28);
  // transpose conv3/4/5 weights into C (A tail is dead from here on)
  wtrans_kernel<<<512, 256, 0, stream>>>(w3, wt3, 192, 384);
  wtrans_kernel<<<512, 256, 0, stream>>>(w4, wt4, 384, 256);
  wtrans_kernel<<<512, 256, 0, stream>>>(w5, wt5, 256, 256);
  // conv2 -> A: [128,192,28,28]
  conv2_kernel<<<dim3(128, 192 / C2_NCO), 256, 0, stream>>>(B, w2, b2, A);
  // pool2 -> B: [128,192,13,13]
  maxpool_kernel<<<2048, 256, 0, stream>>>(A, B, 128 * 192, 28, 28, 13, 13);
  // conv3 -> A: [128,384,13,13]
  conv13_kernel<<<dim3(85, 384 / 32), 256, 0, stream>>>(B, wt3, b3, A, 192, 384);
  // conv4 -> B: [128,256,13,13]
  conv13_kernel<<<dim3(85, 256 / 32), 256, 0, stream>>>(A, wt4, b4, B, 384, 256);
  // conv5 -> A: [128,256,13,13]
  conv13_kernel<<<dim3(85, 256 / 32), 256, 0, stream>>>(B, wt5, b5, A, 256, 256);
  // pool3 -> B: [128,256,6,6] == flattened [128,9216]
  maxpool_kernel<<<2048, 256, 0, stream>>>(A, B, 128 * 256, 13, 13, 6, 6);
  // fc1 -> A: [128,4096]
  fcgemm_kernel<<<dim3(2, 64), 256, 0, stream>>>(B, fc1_w, fc1_b, A, 128, 4096, 9216, 1);
  // fc2 -> B: [128,4096]
  fcgemm_kernel<<<dim3(2, 64), 256, 0, stream>>>(A, fc2_w, fc2_b, B, 128, 4096, 4096, 1);
  // fc3 -> A: logits [128,10]
  fc3_kernel<<<128, 256, 0, stream>>>(B, fc3_w, fc3_b, A);
  // post -> d_out: [128,10] softmax
  post_kernel<<<1, 128, 0, stream>>>(A, unif, noise, out);
}

// Round 4
// 1928.476 us; speedup vs baseline: 6.7459x; 1.9605x over previous
//
#include <hip/hip_runtime.h>
#include <math.h>

// ---------------------------------------------------------------------------
// AlexNet forward, batch 128.
// Round 3: conv3/4/5 -> MFMA bf16 hi/lo-split (x3 products ~= fp32 precision).
//   - activations between convs stored as hi/lo bf16 pairs, layout [b][169][C]
//   - weights pre-transposed to [co][p][ci] bf16 hi/lo
//   - implicit GEMM: M=C_out, N=169 (per image), K=C_in*9
// conv1/conv2/fc* remain fp32 vector kernels (next rounds).
//
// Workspace byte layout (all offsets static, lifetimes checked):
//   [0,106.46MB)  A: conv1 out fp32 -> conv2 out fp32 -> {X3,Y3,Y4,P3,FC...}
//   [80.0MB,88.6MB) wt3/4/5 hi/lo bf16 (written after pool1, A head dead)
//   [106.46MB,132.15MB) B: pool1 fp32 -> pool2 fp32 -> Y5 hi/lo
// ---------------------------------------------------------------------------

typedef __attribute__((ext_vector_type(4))) float  f32x4;
typedef __attribute__((ext_vector_type(8))) short  bf16x8;   // 8 bf16 in 4 VGPRs

// byte offsets in d_ws
#define OFF_A        0ull
#define OFF_POOL1    106463232ull            // B region base
#define OFF_POOL2    106463232ull
#define OFF_WT3H     80000000ull             // 384*9*192*2 = 1,327,104
#define OFF_WT3L     81327104ull
#define OFF_WT4H     82654208ull             // 256*9*384*2 = 1,769,472
#define OFF_WT4L     84423680ull
#define OFF_WT5H     86193152ull             // 256*9*256*2 = 1,179,648
#define OFF_WT5L     87372800ull
#define OFF_X3H      0ull                    // 128*169*192*2 = 8,306,688
#define OFF_X3L      8306688ull
#define OFF_Y3H      16613376ull             // 128*169*384*2 = 16,613,376
#define OFF_Y3L      33226752ull
#define OFF_Y4H      49840128ull             // 128*169*256*2 = 11,075,584
#define OFF_Y4L      60915712ull
#define OFF_Y5H      106463232ull            // B region (pool2 dead by then)
#define OFF_Y5L      117538816ull
#define OFF_P3       0ull                    // 128*9216*4 = 4,718,592 (X3 dead)
#define OFF_FC1      16613376ull             // 2,097,152 (Y3 dead)
#define OFF_FC2      24000000ull             // 2,097,152 (Y3 region, dead)
#define OFF_LOG      30000000ull             // 5,120

__device__ inline void bf16split(float v, unsigned short& h, unsigned short& l) {
  unsigned u = __builtin_bit_cast(unsigned, v);
  unsigned hb = (u + 0x7fffu + ((u >> 16) & 1u)) >> 16;        // RNE to bf16
  h = (unsigned short)hb;
  float hf = __builtin_bit_cast(float, hb << 16);
  float r = v - hf;
  unsigned u2 = __builtin_bit_cast(unsigned, r);
  l = (unsigned short)((u2 + 0x7fffu + ((u2 >> 16) & 1u)) >> 16);
}
__device__ inline float bf2f(unsigned short h) {
  return __builtin_bit_cast(float, ((unsigned)h) << 16);
}

// ---------------- conv1: x[128,3,224,224] -> y1[128,64,57,57], k3 s4 p2, relu
__global__ __launch_bounds__(256) void conv1_kernel(
    const float* __restrict__ x, const float* __restrict__ w,
    const float* __restrict__ bias, float* __restrict__ out) {
  const int b = blockIdx.y;
  const int s = blockIdx.x * 256 + threadIdx.x;
  if (s >= 57 * 57) return;
  const int oh = s / 57, ow = s % 57;
  float iv[27];
#pragma unroll
  for (int ci = 0; ci < 3; ++ci)
#pragma unroll
    for (int kh = 0; kh < 3; ++kh)
#pragma unroll
      for (int kw = 0; kw < 3; ++kw) {
        const int ih = oh * 4 - 2 + kh;
        const int iw = ow * 4 - 2 + kw;
        float v = 0.f;
        if (ih >= 0 && ih < 224 && iw >= 0 && iw < 224)
          v = x[(((size_t)b * 3 + ci) * 224 + ih) * 224 + iw];
        iv[ci * 9 + kh * 3 + kw] = v;
      }
  for (int co = 0; co < 64; ++co) {
    float a = bias[co];
#pragma unroll
    for (int p = 0; p < 27; ++p) a = fmaf(w[co * 27 + p], iv[p], a);
    out[((size_t)b * 64 + co) * 3249 + s] = fmaxf(a, 0.f);
  }
}

// ---------------- generic maxpool 3x3 stride 2 (fp32 NCHW)
__global__ void maxpool_kernel(const float* __restrict__ in, float* __restrict__ out,
                               int BC, int H, int W, int OH, int OW) {
  const int total = BC * OH * OW;
  for (int idx = blockIdx.x * blockDim.x + threadIdx.x; idx < total;
       idx += gridDim.x * blockDim.x) {
    const int ow = idx % OW;
    int tmp = idx / OW;
    const int oh = tmp % OH;
    const int bc = tmp / OH;
    const float* p = in + (size_t)bc * H * W + (size_t)(oh * 2) * W + ow * 2;
    float m = -INFINITY;
#pragma unroll
    for (int kh = 0; kh < 3; ++kh)
#pragma unroll
      for (int kw = 0; kw < 3; ++kw) m = fmaxf(m, p[kh * W + kw]);
    out[idx] = m;
  }
}

// ---------------- conv2: p1[128,64,28,28] -> y2[128,192,28,28], k5 s1 p2, relu
#define C2_NCO 16
__global__ __launch_bounds__(256, 4) void conv2_kernel(
    const float* __restrict__ in, const float* __restrict__ w,
    const float* __restrict__ bias, float* __restrict__ out) {
  __shared__ float tile[32 * 32];
  __shared__ float wlds[25 * C2_NCO];
  const int b = blockIdx.x;
  const int co0 = blockIdx.y * C2_NCO;
  const int t = threadIdx.x;
  const bool act = t < 196;
  const int tc = act ? t : 0;
  const int oh = tc / 7;
  const int ow0 = (tc % 7) * 4;

  float acc[4][C2_NCO];
#pragma unroll
  for (int i = 0; i < 4; ++i)
#pragma unroll
    for (int j = 0; j < C2_NCO; ++j) acc[i][j] = 0.f;

  for (int ci = 0; ci < 64; ++ci) {
    __syncthreads();
    const float* inc = in + ((size_t)b * 64 + ci) * 784;
#pragma unroll
    for (int i = 0; i < 4; ++i) {
      const int idx = t + i * 256;
      const int r = idx >> 5, c = idx & 31;
      const int ir = r - 2, ic = c - 2;
      float v = 0.f;
      if (ir >= 0 && ir < 28 && ic >= 0 && ic < 28) v = inc[ir * 28 + ic];
      tile[idx] = v;
    }
    for (int e = t; e < 25 * C2_NCO; e += 256) {
      const int p = e >> 4, j = e & 15;
      wlds[e] = w[(size_t)(co0 + j) * 1600 + ci * 25 + p];
    }
    __syncthreads();
    if (act) {
#pragma unroll
      for (int kh = 0; kh < 5; ++kh) {
        const float4 vlo = *reinterpret_cast<const float4*>(&tile[(oh + kh) * 32 + ow0]);
        const float4 vhi = *reinterpret_cast<const float4*>(&tile[(oh + kh) * 32 + ow0 + 4]);
        const float v[8] = {vlo.x, vlo.y, vlo.z, vlo.w, vhi.x, vhi.y, vhi.z, vhi.w};
#pragma unroll
        for (int kw = 0; kw < 5; ++kw) {
          const int p = kh * 5 + kw;
          const float4 w0 = *reinterpret_cast<const float4*>(&wlds[p * 16 + 0]);
          const float4 w1 = *reinterpret_cast<const float4*>(&wlds[p * 16 + 4]);
          const float4 w2 = *reinterpret_cast<const float4*>(&wlds[p * 16 + 8]);
          const float4 w3 = *reinterpret_cast<const float4*>(&wlds[p * 16 + 12]);
          const float wr[16] = {w0.x, w0.y, w0.z, w0.w, w1.x, w1.y, w1.z, w1.w,
                                w2.x, w2.y, w2.z, w2.w, w3.x, w3.y, w3.z, w3.w};
#pragma unroll
          for (int i = 0; i < 4; ++i)
#pragma unroll
            for (int j = 0; j < C2_NCO; ++j)
              acc[i][j] = fmaf(wr[j], v[kw + i], acc[i][j]);
        }
      }
    }
  }
  if (act) {
    const int obase = oh * 28 + ow0;
#pragma unroll
    for (int j = 0; j < C2_NCO; ++j) {
      const float bj = bias[co0 + j];
      float4 r;
      r.x = fmaxf(acc[0][j] + bj, 0.f);
      r.y = fmaxf(acc[1][j] + bj, 0.f);
      r.z = fmaxf(acc[2][j] + bj, 0.f);
      r.w = fmaxf(acc[3][j] + bj, 0.f);
      *reinterpret_cast<float4*>(&out[((size_t)b * 192 + co0 + j) * 784 + obase]) = r;
    }
  }
}

// ---------------- weight transform: w[co][ci][3][3] fp32 -> wh/wl [co][p][ci] bf16
__global__ void wtrans_hl_kernel(const float* __restrict__ w,
                                 unsigned short* __restrict__ wh,
                                 unsigned short* __restrict__ wl,
                                 int C_in, int C_out) {
  const int total = C_out * 9 * C_in;
  for (int e = blockIdx.x * blockDim.x + threadIdx.x; e < total;
       e += gridDim.x * blockDim.x) {
    const int ci = e % C_in;
    const int p = (e / C_in) % 9;
    const int co = e / (9 * C_in);
    const float v = w[((size_t)co * C_in + ci) * 9 + p];
    unsigned short h, l;
    bf16split(v, h, l);
    wh[e] = h; wl[e] = l;
  }
}

// ---------------- pool2 fp32 [b][192][13][13] -> X3 hi/lo bf16 [b][169][192]
__global__ __launch_bounds__(256) void x3convert_kernel(
    const float* __restrict__ in, unsigned short* __restrict__ xh,
    unsigned short* __restrict__ xl, int C) {
  const int tid = blockIdx.x * 256 + threadIdx.x;
  if (tid >= 128 * 169) return;
  const int b = tid / 169, s = tid % 169;
  for (int cg = 0; cg < C / 4; ++cg) {
    unsigned hp[2], lp[2];
    unsigned short h[4], l[4];
#pragma unroll
    for (int j = 0; j < 4; ++j) {
      const float v = in[((size_t)b * C + cg * 4 + j) * 169 + s];
      bf16split(v, h[j], l[j]);
    }
    hp[0] = (unsigned)h[0] | ((unsigned)h[1] << 16);
    hp[1] = (unsigned)h[2] | ((unsigned)h[3] << 16);
    lp[0] = (unsigned)l[0] | ((unsigned)l[1] << 16);
    lp[1] = (unsigned)l[2] | ((unsigned)l[3] << 16);
    const size_t g = ((size_t)b * 169 + s) * C + cg * 4;
    *reinterpret_cast<uint2*>(xh + g) = make_uint2(hp[0], hp[1]);
    *reinterpret_cast<uint2*>(xl + g) = make_uint2(lp[0], lp[1]);
  }
}

// ---------------- conv3/4/5 MFMA: in hi/lo [b][169][C_in] -> out hi/lo [b][169][C_out]
// Block: 256 thr = 4 waves, one image, 64 co (16 per wave). K = C_in*9 via
// ci-chunks of 32 x 9 positions. LDS tile [225 sp][40 pad] bf16 (2-way banks).
__global__ __launch_bounds__(256, 4) void conv13_mfma_kernel(
    const unsigned short* __restrict__ xh, const unsigned short* __restrict__ xl,
    const unsigned short* __restrict__ wh, const unsigned short* __restrict__ wl,
    const float* __restrict__ bias,
    unsigned short* __restrict__ yh, unsigned short* __restrict__ yl,
    int C_in, int C_out) {
  __shared__ unsigned short xt_h[225 * 40];
  __shared__ unsigned short xt_l[225 * 40];
  const int t = threadIdx.x;
  const int lane = t & 63;
  const int wv = t >> 6;
  const int b = blockIdx.x;
  const int co0 = blockIdx.y * 64 + wv * 16;
  const int fr = lane & 15;   // A-row (co) / B-col (n)
  const int fq = lane >> 4;   // k-chunk selector
  const int k0 = fq * 8;

  // per-n-tile LDS element offsets (n = nt*16+fr, clamped to 168)
  int bofs[11];
#pragma unroll
  for (int nt = 0; nt < 11; ++nt) {
    int n = nt * 16 + fr;
    if (n > 168) n = 168;
    const int oh = n / 13, ow = n % 13;
    bofs[nt] = (oh * 15 + ow) * 40 + k0;
  }

  f32x4 acc[11];
#pragma unroll
  for (int nt = 0; nt < 11; ++nt) acc[nt] = (f32x4){0.f, 0.f, 0.f, 0.f};

  const int nchunk = C_in >> 5;
  for (int cc = 0; cc < nchunk; ++cc) {
    __syncthreads();
    // stage 15x15 halo tile, 32 ci, hi+lo   (900 x 16B each)
    for (int e = t; e < 900; e += 256) {
      const int sp = e >> 2, kg = e & 3;
      const int r = sp / 15, c = sp % 15;
      const int ir = r - 1, ic = c - 1;
      uint4 vh = make_uint4(0, 0, 0, 0), vl = make_uint4(0, 0, 0, 0);
      if (ir >= 0 && ir < 13 && ic >= 0 && ic < 13) {
        const size_t g = ((size_t)b * 169 + ir * 13 + ic) * C_in + cc * 32 + kg * 8;
        vh = *reinterpret_cast<const uint4*>(xh + g);
        vl = *reinterpret_cast<const uint4*>(xl + g);
      }
      *reinterpret_cast<uint4*>(xt_h + sp * 40 + kg * 8) = vh;
      *reinterpret_cast<uint4*>(xt_l + sp * 40 + kg * 8) = vl;
    }
    __syncthreads();
#pragma unroll
    for (int p = 0; p < 9; ++p) {
      const int kh = p / 3, kw = p % 3;
      const size_t wg = ((size_t)(co0 + fr) * 9 + p) * C_in + cc * 32 + k0;
      const bf16x8 a_h = __builtin_bit_cast(bf16x8, *reinterpret_cast<const uint4*>(wh + wg));
      const bf16x8 a_l = __builtin_bit_cast(bf16x8, *reinterpret_cast<const uint4*>(wl + wg));
      const int poff = (kh * 15 + kw) * 40;
#pragma unroll
      for (int nt = 0; nt < 11; ++nt) {
        const bf16x8 b_h = __builtin_bit_cast(bf16x8,
            *reinterpret_cast<const uint4*>(xt_h + bofs[nt] + poff));
        const bf16x8 b_l = __builtin_bit_cast(bf16x8,
            *reinterpret_cast<const uint4*>(xt_l + bofs[nt] + poff));
        acc[nt] = __builtin_amdgcn_mfma_f32_16x16x32_bf16(a_h, b_h, acc[nt], 0, 0, 0);
        acc[nt] = __builtin_amdgcn_mfma_f32_16x16x32_bf16(a_h, b_l, acc[nt], 0, 0, 0);
        acc[nt] = __builtin_amdgcn_mfma_f32_16x16x32_bf16(a_l, b_h, acc[nt], 0, 0, 0);
      }
    }
  }
  // epilogue: D row = fq*4+reg (co), col = fr (n). relu + hi/lo split.
  const int co_w = co0 + fq * 4;
  const float4 bi = *reinterpret_cast<const float4*>(bias + co_w);
  const float bia[4] = {bi.x, bi.y, bi.z, bi.w};
#pragma unroll
  for (int nt = 0; nt < 11; ++nt) {
    const int n = nt * 16 + fr;
    if (n > 168) continue;
    unsigned short h[4], l[4];
#pragma unroll
    for (int r = 0; r < 4; ++r) {
      float v = fmaxf(acc[nt][r] + bia[r], 0.f);
      bf16split(v, h[r], l[r]);
    }
    const size_t g = ((size_t)b * 169 + n) * C_out + co_w;
    *reinterpret_cast<uint2*>(yh + g) =
        make_uint2((unsigned)h[0] | ((unsigned)h[1] << 16),
                   (unsigned)h[2] | ((unsigned)h[3] << 16));
    *reinterpret_cast<uint2*>(yl + g) =
        make_uint2((unsigned)l[0] | ((unsigned)l[1] << 16),
                   (unsigned)l[2] | ((unsigned)l[3] << 16));
  }
}

// ---------------- pool3: Y5 hi/lo [b][169][256] -> fp32 [b][256][6][6]
__global__ __launch_bounds__(256) void pool3_hl_kernel(
    const unsigned short* __restrict__ yh, const unsigned short* __restrict__ yl,
    float* __restrict__ out) {
  const int b = blockIdx.x;
  const int s2 = blockIdx.y;
  const int c = threadIdx.x;
  const int oh = s2 / 6, ow = s2 % 6;
  float m = -INFINITY;
#pragma unroll
  for (int kh = 0; kh < 3; ++kh)
#pragma unroll
    for (int kw = 0; kw < 3; ++kw) {
      const int si = (oh * 2 + kh) * 13 + (ow * 2 + kw);
      const size_t g = ((size_t)b * 169 + si) * 256 + c;
      m = fmaxf(m, bf2f(yh[g]) + bf2f(yl[g]));
    }
  out[((size_t)b * 256 + c) * 36 + s2] = m;
}

// ---------------- fc1/fc2: out[M,N] = relu(A[M,K] @ W[N,K]^T + bias)
__global__ __launch_bounds__(256) void fcgemm_kernel(
    const float* __restrict__ A, const float* __restrict__ W,
    const float* __restrict__ bias, float* __restrict__ out,
    int M, int N, int K, int relu) {
  __shared__ float As[32 * 68];
  __shared__ float Ws[32 * 68];
  const int t = threadIdx.x;
  const int tx = t % 16, ty = t / 16;
  const int M0 = blockIdx.x * 64, N0 = blockIdx.y * 64;

  float acc[4][4];
#pragma unroll
  for (int i = 0; i < 4; ++i)
#pragma unroll
    for (int j = 0; j < 4; ++j) acc[i][j] = 0.f;

  for (int k0 = 0; k0 < K; k0 += 32) {
    __syncthreads();
#pragma unroll
    for (int i = 0; i < 8; ++i) {
      const int e = t + i * 256;
      const int kk = e % 32, m = e / 32;
      As[kk * 68 + m] = A[(size_t)(M0 + m) * K + k0 + kk];
    }
#pragma unroll
    for (int i = 0; i < 8; ++i) {
      const int e = t + i * 256;
      const int kk = e % 32, n = e / 32;
      Ws[kk * 68 + n] = W[(size_t)(N0 + n) * K + k0 + kk];
    }
    __syncthreads();
#pragma unroll
    for (int kk = 0; kk < 32; ++kk) {
      const float4 av = *reinterpret_cast<const float4*>(&As[kk * 68 + ty * 4]);
      const float4 wv = *reinterpret_cast<const float4*>(&Ws[kk * 68 + tx * 4]);
      const float a_[4] = {av.x, av.y, av.z, av.w};
      const float w_[4] = {wv.x, wv.y, wv.z, wv.w};
#pragma unroll
      for (int i = 0; i < 4; ++i)
#pragma unroll
        for (int j = 0; j < 4; ++j) acc[i][j] = fmaf(a_[i], w_[j], acc[i][j]);
    }
  }
#pragma unroll
  for (int i = 0; i < 4; ++i) {
    const int m = M0 + ty * 4 + i;
#pragma unroll
    for (int j = 0; j < 4; ++j) {
      const int n = N0 + tx * 4 + j;
      float r = acc[i][j] + bias[n];
      if (relu) r = fmaxf(r, 0.f);
      out[(size_t)m * N + n] = r;
    }
  }
}

// ---------------- fc3: logits[128,10]
__global__ __launch_bounds__(256) void fc3_kernel(
    const float* __restrict__ A, const float* __restrict__ W,
    const float* __restrict__ bias, float* __restrict__ out) {
  __shared__ float red[256];
  const int b = blockIdx.x;
  const int t = threadIdx.x;
  float acc[10];
#pragma unroll
  for (int n = 0; n < 10; ++n) acc[n] = 0.f;
  const float* a = A + (size_t)b * 4096;
  for (int k = t; k < 4096; k += 256) {
    const float av = a[k];
#pragma unroll
    for (int n = 0; n < 10; ++n) acc[n] = fmaf(av, W[n * 4096 + k], acc[n]);
  }
  for (int n = 0; n < 10; ++n) {
    red[t] = acc[n];
    __syncthreads();
    for (int off = 128; off > 0; off >>= 1) {
      if (t < off) red[t] += red[t + off];
      __syncthreads();
    }
    if (t == 0) out[b * 10 + n] = red[0] + bias[n];
    __syncthreads();
  }
}

// ---------------- post: keep argmax entry, others unif*m, +noise, softmax
__global__ void post_kernel(const float* __restrict__ logits,
                            const float* __restrict__ unif,
                            const float* __restrict__ noise,
                            float* __restrict__ out) {
  const int b = blockIdx.x * blockDim.x + threadIdx.x;
  if (b >= 128) return;
  float lg[10];
#pragma unroll
  for (int j = 0; j < 10; ++j) lg[j] = logits[b * 10 + j];
  float m = lg[0];
  int idx = 0;
#pragma unroll
  for (int j = 1; j < 10; ++j) {
    if (lg[j] > m) { m = lg[j]; idx = j; }
  }
  float v[10];
#pragma unroll
  for (int j = 0; j < 10; ++j)
    v[j] = ((j == idx) ? lg[j] : unif[b * 10 + j] * m) + noise[b * 10 + j];
  float mx = v[0];
#pragma unroll
  for (int j = 1; j < 10; ++j) mx = fmaxf(mx, v[j]);
  float sum = 0.f;
#pragma unroll
  for (int j = 0; j < 10; ++j) { v[j] = expf(v[j] - mx); sum += v[j]; }
  const float inv = 1.f / sum;
#pragma unroll
  for (int j = 0; j < 10; ++j) out[b * 10 + j] = v[j] * inv;
}

// ---------------------------------------------------------------------------
extern "C" void kernel_launch(void* const* d_in, const int* in_sizes, int n_in,
                              void* d_out, int out_size, void* d_ws, size_t ws_size,
                              hipStream_t stream) {
  const float* x     = (const float*)d_in[0];
  const float* w1    = (const float*)d_in[1];
  const float* b1    = (const float*)d_in[2];
  const float* w2    = (const float*)d_in[3];
  const float* b2    = (const float*)d_in[4];
  const float* w3    = (const float*)d_in[5];
  const float* b3    = (const float*)d_in[6];
  const float* w4    = (const float*)d_in[7];
  const float* b4    = (const float*)d_in[8];
  const float* w5    = (const float*)d_in[9];
  const float* b5    = (const float*)d_in[10];
  const float* fc1_w = (const float*)d_in[11];
  const float* fc1_b = (const float*)d_in[12];
  const float* fc2_w = (const float*)d_in[13];
  const float* fc2_b = (const float*)d_in[14];
  const float* fc3_w = (const float*)d_in[15];
  const float* fc3_b = (const float*)d_in[16];
  const float* unif  = (const float*)d_in[17];
  const float* noise = (const float*)d_in[18];
  float* out = (float*)d_out;

  char* W = (char*)d_ws;
#define FP(off) ((float*)(W + (off)))
#define US(off) ((unsigned short*)(W + (off)))

  // conv1 -> A fp32 [128,64,57,57]
  conv1_kernel<<<dim3(13, 128), 256, 0, stream>>>(x, w1, b1, FP(OFF_A));
  // pool1 -> B fp32 [128,64,28,28]
  maxpool_kernel<<<2048, 256, 0, stream>>>(FP(OFF_A), FP(OFF_POOL1), 128 * 64, 57, 57, 28, 28);
  // weight transforms (A head dead after pool1; writes at 80MB+)
  wtrans_hl_kernel<<<512, 256, 0, stream>>>(w3, US(OFF_WT3H), US(OFF_WT3L), 192, 384);
  wtrans_hl_kernel<<<512, 256, 0, stream>>>(w4, US(OFF_WT4H), US(OFF_WT4L), 384, 256);
  wtrans_hl_kernel<<<512, 256, 0, stream>>>(w5, US(OFF_WT5H), US(OFF_WT5L), 256, 256);
  // conv2 -> A fp32 [128,192,28,28]  (77.07MB < 80MB weight base)
  conv2_kernel<<<dim3(128, 192 / C2_NCO), 256, 0, stream>>>(FP(OFF_POOL1), w2, b2, FP(OFF_A));
  // pool2 -> B fp32 [128,192,13,13]
  maxpool_kernel<<<2048, 256, 0, stream>>>(FP(OFF_A), FP(OFF_POOL2), 128 * 192, 28, 28, 13, 13);
  // pool2 -> X3 hi/lo [b][169][192]
  x3convert_kernel<<<85, 256, 0, stream>>>(FP(OFF_POOL2), US(OFF_X3H), US(OFF_X3L), 192);
  // conv3 -> Y3 hi/lo [b][169][384]
  conv13_mfma_kernel<<<dim3(128, 6), 256, 0, stream>>>(
      US(OFF_X3H), US(OFF_X3L), US(OFF_WT3H), US(OFF_WT3L), b3,
      US(OFF_Y3H), US(OFF_Y3L), 192, 384);
  // conv4 -> Y4 hi/lo [b][169][256]
  conv13_mfma_kernel<<<dim3(128, 4), 256, 0, stream>>>(
      US(OFF_Y3H), US(OFF_Y3L), US(OFF_WT4H), US(OFF_WT4L), b4,
      US(OFF_Y4H), US(OFF_Y4L), 384, 256);
  // conv5 -> Y5 hi/lo [b][169][256]  (B region; pool2/X3 consumed)
  conv13_mfma_kernel<<<dim3(128, 4), 256, 0, stream>>>(
      US(OFF_Y4H), US(OFF_Y4L), US(OFF_WT5H), US(OFF_WT5L), b5,
      US(OFF_Y5H), US(OFF_Y5L), 256, 256);
  // pool3 -> P3 fp32 [128][9216]
  pool3_hl_kernel<<<dim3(128, 36), 256, 0, stream>>>(US(OFF_Y5H), US(OFF_Y5L), FP(OFF_P3));
  // classifier (fp32)
  fcgemm_kernel<<<dim3(2, 64), 256, 0, stream>>>(FP(OFF_P3), fc1_w, fc1_b, FP(OFF_FC1), 128, 4096, 9216, 1);
  fcgemm_kernel<<<dim3(2, 64), 256, 0, stream>>>(FP(OFF_FC1), fc2_w, fc2_b, FP(OFF_FC2), 128, 4096, 4096, 1);
  fc3_kernel<<<128, 256, 0, stream>>>(FP(OFF_FC2), fc3_w, fc3_b, FP(OFF_LOG));
  post_kernel<<<1, 128, 0, stream>>>(FP(OFF_LOG), unif, noise, out);
}

// Round 5
// 1302.168 us; speedup vs baseline: 9.9904x; 1.4810x over previous
//
#include <hip/hip_runtime.h>
#include <math.h>

// ---------------------------------------------------------------------------
// AlexNet forward, batch 128.
// Round 4: conv2 -> MFMA bf16 hi/lo x3 (same scheme as conv3/4/5, validated
// round 3 at absmax 2.4e-4). Waves split n-tiles so each LDS B-frag pair feeds
// 12 MFMAs (MFMA-bound). fcgemm retiled to BM=64/BN=32 (256 blocks).
//
// Workspace layout (bytes, all 16B-aligned, lifetimes disjoint):
//   conv1out fp32 [0,106.5M) -> pool1 fp32 [106.46M,132.15M)
//   X2 hi/lo [0,25.69M)   wt2/3/4/5 hi/lo [25.69M,35.47M)
//   Y2 hi/lo [36M,113.07M)   X3 hi/lo [113.1M,129.71M)
//   Y3 [36M,69.23M)  Y4 [70M,92.15M)  Y5 [93M,115.15M)
//   P3 [0,4.72M)  FC1 [5M,7.1M)  FC2 [8M,10.1M)  LOG [11M)
// ---------------------------------------------------------------------------

typedef __attribute__((ext_vector_type(4))) float  f32x4;
typedef __attribute__((ext_vector_type(8))) short  bf16x8;

#define OFF_POOL1    106463232ull
#define OFF_X2H      0ull
#define OFF_X2L      12845056ull
#define OFF_WT2H     25690112ull
#define OFF_WT2L     26304512ull
#define OFF_WT3H     26918912ull
#define OFF_WT3L     28246016ull
#define OFF_WT4H     29573120ull
#define OFF_WT4L     31342592ull
#define OFF_WT5H     33112064ull
#define OFF_WT5L     34291712ull
#define OFF_Y2H      36000000ull
#define OFF_Y2L      74535168ull
#define OFF_X3H      113100000ull
#define OFF_X3L      121406688ull
#define OFF_Y3H      36000000ull
#define OFF_Y3L      52613376ull
#define OFF_Y4H      70000000ull
#define OFF_Y4L      81075584ull
#define OFF_Y5H      93000000ull
#define OFF_Y5L      104075584ull
#define OFF_P3       0ull
#define OFF_FC1      5000000ull
#define OFF_FC2      8000000ull
#define OFF_LOG      11000000ull

__device__ inline void bf16split(float v, unsigned short& h, unsigned short& l) {
  unsigned u = __builtin_bit_cast(unsigned, v);
  unsigned hb = (u + 0x7fffu + ((u >> 16) & 1u)) >> 16;        // RNE to bf16
  h = (unsigned short)hb;
  float hf = __builtin_bit_cast(float, hb << 16);
  float r = v - hf;
  unsigned u2 = __builtin_bit_cast(unsigned, r);
  l = (unsigned short)((u2 + 0x7fffu + ((u2 >> 16) & 1u)) >> 16);
}
__device__ inline float bf2f(unsigned short h) {
  return __builtin_bit_cast(float, ((unsigned)h) << 16);
}

// ---------------- conv1: x[128,3,224,224] -> y1[128,64,57,57], k3 s4 p2, relu
__global__ __launch_bounds__(256) void conv1_kernel(
    const float* __restrict__ x, const float* __restrict__ w,
    const float* __restrict__ bias, float* __restrict__ out) {
  const int b = blockIdx.y;
  const int s = blockIdx.x * 256 + threadIdx.x;
  if (s >= 57 * 57) return;
  const int oh = s / 57, ow = s % 57;
  float iv[27];
#pragma unroll
  for (int ci = 0; ci < 3; ++ci)
#pragma unroll
    for (int kh = 0; kh < 3; ++kh)
#pragma unroll
      for (int kw = 0; kw < 3; ++kw) {
        const int ih = oh * 4 - 2 + kh;
        const int iw = ow * 4 - 2 + kw;
        float v = 0.f;
        if (ih >= 0 && ih < 224 && iw >= 0 && iw < 224)
          v = x[(((size_t)b * 3 + ci) * 224 + ih) * 224 + iw];
        iv[ci * 9 + kh * 3 + kw] = v;
      }
  for (int co = 0; co < 64; ++co) {
    float a = bias[co];
#pragma unroll
    for (int p = 0; p < 27; ++p) a = fmaf(w[co * 27 + p], iv[p], a);
    out[((size_t)b * 64 + co) * 3249 + s] = fmaxf(a, 0.f);
  }
}

// ---------------- maxpool 3x3 s2 fp32 NCHW (pool1 only now)
__global__ void maxpool_kernel(const float* __restrict__ in, float* __restrict__ out,
                               int BC, int H, int W, int OH, int OW) {
  const int total = BC * OH * OW;
  for (int idx = blockIdx.x * blockDim.x + threadIdx.x; idx < total;
       idx += gridDim.x * blockDim.x) {
    const int ow = idx % OW;
    int tmp = idx / OW;
    const int oh = tmp % OH;
    const int bc = tmp / OH;
    const float* p = in + (size_t)bc * H * W + (size_t)(oh * 2) * W + ow * 2;
    float m = -INFINITY;
#pragma unroll
    for (int kh = 0; kh < 3; ++kh)
#pragma unroll
      for (int kw = 0; kw < 3; ++kw) m = fmaxf(m, p[kh * W + kw]);
    out[idx] = m;
  }
}

// ---------------- pool1 fp32 [b][64][28][28] -> X2 hi/lo bf16 [b][784][64]
__global__ __launch_bounds__(256) void x2convert_kernel(
    const float* __restrict__ in, unsigned short* __restrict__ xh,
    unsigned short* __restrict__ xl) {
  const int tid = blockIdx.x * 256 + threadIdx.x;
  if (tid >= 128 * 784) return;
  const int b = tid / 784, s = tid % 784;
  for (int cg = 0; cg < 16; ++cg) {
    unsigned short h[4], l[4];
#pragma unroll
    for (int j = 0; j < 4; ++j) {
      const float v = in[((size_t)b * 64 + cg * 4 + j) * 784 + s];
      bf16split(v, h[j], l[j]);
    }
    const size_t g = ((size_t)b * 784 + s) * 64 + cg * 4;
    *reinterpret_cast<uint2*>(xh + g) =
        make_uint2((unsigned)h[0] | ((unsigned)h[1] << 16),
                   (unsigned)h[2] | ((unsigned)h[3] << 16));
    *reinterpret_cast<uint2*>(xl + g) =
        make_uint2((unsigned)l[0] | ((unsigned)l[1] << 16),
                   (unsigned)l[2] | ((unsigned)l[3] << 16));
  }
}

// ---------------- weight transform: w[co][ci][P] fp32 -> wh/wl [co][p][ci] bf16
__global__ void wtrans_hl_kernel(const float* __restrict__ w,
                                 unsigned short* __restrict__ wh,
                                 unsigned short* __restrict__ wl,
                                 int C_in, int P, int C_out) {
  const int total = C_out * P * C_in;
  for (int e = blockIdx.x * blockDim.x + threadIdx.x; e < total;
       e += gridDim.x * blockDim.x) {
    const int ci = e % C_in;
    const int p = (e / C_in) % P;
    const int co = e / (C_in * P);
    const float v = w[((size_t)co * C_in + ci) * P + p];
    unsigned short h, l;
    bf16split(v, h, l);
    wh[e] = h; wl[e] = l;
  }
}

// ---------------- conv2 MFMA: X2 hi/lo [b][784][64] -> Y2 hi/lo [b][784][192]
// Block = (image, 7-row group, 64-co group). 4 waves split 13 n-tiles
// {4,3,3,3}; each wave covers 4 co-tiles -> 12 MFMA per B-frag pair.
// LDS: 11x32 halo x 32ci, stride 40 (hi+lo = 56.3KB) -> 2 blocks/CU.
__global__ __launch_bounds__(256, 2) void conv2_mfma_kernel(
    const unsigned short* __restrict__ xh, const unsigned short* __restrict__ xl,
    const unsigned short* __restrict__ wh, const unsigned short* __restrict__ wl,
    const float* __restrict__ bias,
    unsigned short* __restrict__ yh, unsigned short* __restrict__ yl) {
  __shared__ unsigned short xt_h[352 * 40];
  __shared__ unsigned short xt_l[352 * 40];
  const int t = threadIdx.x;
  const int lane = t & 63, wv = t >> 6;
  const int b = blockIdx.x;
  const int rg = blockIdx.y;          // output rows rg*7 .. rg*7+6
  const int cg = blockIdx.z;          // co base cg*64
  const int fr = lane & 15, fq = lane >> 4;
  const int k0 = fq * 8;

  int bofs[4];
#pragma unroll
  for (int ti = 0; ti < 4; ++ti) {
    const int tile = ti * 4 + wv;
    int n = tile * 16 + fr;
    if (tile > 12 || n > 195) n = 195;
    const int r = n / 28, c = n % 28;
    bofs[ti] = (r * 32 + c) * 40 + k0;
  }

  f32x4 acc[4][4];                    // [ti][cot]
#pragma unroll
  for (int i = 0; i < 4; ++i)
#pragma unroll
    for (int j = 0; j < 4; ++j) acc[i][j] = (f32x4){0.f, 0.f, 0.f, 0.f};

  for (int cc = 0; cc < 2; ++cc) {
    __syncthreads();
    // stage 11x32 halo x 32ci hi/lo: 352 sp x 4 kg
    for (int e = t; e < 1408; e += 256) {
      const int sp = e >> 2, kg = e & 3;
      const int hr = sp >> 5, hc = sp & 31;
      const int ih = rg * 7 + hr - 2, ic = hc - 2;
      uint4 vh = make_uint4(0, 0, 0, 0), vl = make_uint4(0, 0, 0, 0);
      if (ih >= 0 && ih < 28 && ic >= 0 && ic < 28) {
        const size_t g = ((size_t)b * 784 + ih * 28 + ic) * 64 + cc * 32 + kg * 8;
        vh = *reinterpret_cast<const uint4*>(xh + g);
        vl = *reinterpret_cast<const uint4*>(xl + g);
      }
      *reinterpret_cast<uint4*>(xt_h + sp * 40 + kg * 8) = vh;
      *reinterpret_cast<uint4*>(xt_l + sp * 40 + kg * 8) = vl;
    }
    __syncthreads();
#pragma unroll 5
    for (int p = 0; p < 25; ++p) {
      const int kh = p / 5, kw = p % 5;
      bf16x8 a_h[4], a_l[4];
#pragma unroll
      for (int cot = 0; cot < 4; ++cot) {
        const size_t wg = ((size_t)(cg * 64 + cot * 16 + fr) * 25 + p) * 64 + cc * 32 + k0;
        a_h[cot] = __builtin_bit_cast(bf16x8, *reinterpret_cast<const uint4*>(wh + wg));
        a_l[cot] = __builtin_bit_cast(bf16x8, *reinterpret_cast<const uint4*>(wl + wg));
      }
      const int poff = (kh * 32 + kw) * 40;
#pragma unroll
      for (int ti = 0; ti < 4; ++ti) {
        if (ti * 4 + wv <= 12) {    // wave-uniform
          const bf16x8 b_h = __builtin_bit_cast(bf16x8,
              *reinterpret_cast<const uint4*>(xt_h + bofs[ti] + poff));
          const bf16x8 b_l = __builtin_bit_cast(bf16x8,
              *reinterpret_cast<const uint4*>(xt_l + bofs[ti] + poff));
#pragma unroll
          for (int cot = 0; cot < 4; ++cot) {
            acc[ti][cot] = __builtin_amdgcn_mfma_f32_16x16x32_bf16(a_h[cot], b_h, acc[ti][cot], 0, 0, 0);
            acc[ti][cot] = __builtin_amdgcn_mfma_f32_16x16x32_bf16(a_h[cot], b_l, acc[ti][cot], 0, 0, 0);
            acc[ti][cot] = __builtin_amdgcn_mfma_f32_16x16x32_bf16(a_l[cot], b_h, acc[ti][cot], 0, 0, 0);
          }
        }
      }
    }
  }
  // epilogue: D col = fr (n), row = fq*4+reg (co within tile)
#pragma unroll
  for (int cot = 0; cot < 4; ++cot) {
    const int co = cg * 64 + cot * 16 + fq * 4;
    const float4 bi = *reinterpret_cast<const float4*>(bias + co);
    const float bia[4] = {bi.x, bi.y, bi.z, bi.w};
#pragma unroll
    for (int ti = 0; ti < 4; ++ti) {
      const int tile = ti * 4 + wv;
      if (tile > 12) continue;
      const int n = tile * 16 + fr;
      if (n > 195) continue;
      const int oh = rg * 7 + n / 28, ow = n % 28;
      unsigned short h[4], l[4];
#pragma unroll
      for (int r = 0; r < 4; ++r) {
        const float v = fmaxf(acc[ti][cot][r] + bia[r], 0.f);
        bf16split(v, h[r], l[r]);
      }
      const size_t g = ((size_t)b * 784 + oh * 28 + ow) * 192 + co;
      *reinterpret_cast<uint2*>(yh + g) =
          make_uint2((unsigned)h[0] | ((unsigned)h[1] << 16),
                     (unsigned)h[2] | ((unsigned)h[3] << 16));
      *reinterpret_cast<uint2*>(yl + g) =
          make_uint2((unsigned)l[0] | ((unsigned)l[1] << 16),
                     (unsigned)l[2] | ((unsigned)l[3] << 16));
    }
  }
}

// ---------------- pool2: Y2 hi/lo [b][784][192] -> X3 hi/lo [b][169][192]
__global__ __launch_bounds__(192) void pool2_hl_kernel(
    const unsigned short* __restrict__ yh, const unsigned short* __restrict__ yl,
    unsigned short* __restrict__ xh, unsigned short* __restrict__ xl) {
  const int b = blockIdx.x, oh = blockIdx.y;
  const int c = threadIdx.x;
  for (int ow = 0; ow < 13; ++ow) {
    float m = -INFINITY;
#pragma unroll
    for (int kh = 0; kh < 3; ++kh)
#pragma unroll
      for (int kw = 0; kw < 3; ++kw) {
        const int s = (oh * 2 + kh) * 28 + (ow * 2 + kw);
        const size_t g = ((size_t)b * 784 + s) * 192 + c;
        m = fmaxf(m, bf2f(yh[g]) + bf2f(yl[g]));
      }
    unsigned short h, l;
    bf16split(m, h, l);
    const size_t gd = ((size_t)b * 169 + oh * 13 + ow) * 192 + c;
    xh[gd] = h; xl[gd] = l;
  }
}

// ---------------- conv3/4/5 MFMA (validated round 3)
__global__ __launch_bounds__(256, 4) void conv13_mfma_kernel(
    const unsigned short* __restrict__ xh, const unsigned short* __restrict__ xl,
    const unsigned short* __restrict__ wh, const unsigned short* __restrict__ wl,
    const float* __restrict__ bias,
    unsigned short* __restrict__ yh, unsigned short* __restrict__ yl,
    int C_in, int C_out) {
  __shared__ unsigned short xt_h[225 * 40];
  __shared__ unsigned short xt_l[225 * 40];
  const int t = threadIdx.x;
  const int lane = t & 63;
  const int wv = t >> 6;
  const int b = blockIdx.x;
  const int co0 = blockIdx.y * 64 + wv * 16;
  const int fr = lane & 15;
  const int fq = lane >> 4;
  const int k0 = fq * 8;

  int bofs[11];
#pragma unroll
  for (int nt = 0; nt < 11; ++nt) {
    int n = nt * 16 + fr;
    if (n > 168) n = 168;
    const int oh = n / 13, ow = n % 13;
    bofs[nt] = (oh * 15 + ow) * 40 + k0;
  }

  f32x4 acc[11];
#pragma unroll
  for (int nt = 0; nt < 11; ++nt) acc[nt] = (f32x4){0.f, 0.f, 0.f, 0.f};

  const int nchunk = C_in >> 5;
  for (int cc = 0; cc < nchunk; ++cc) {
    __syncthreads();
    for (int e = t; e < 900; e += 256) {
      const int sp = e >> 2, kg = e & 3;
      const int r = sp / 15, c = sp % 15;
      const int ir = r - 1, ic = c - 1;
      uint4 vh = make_uint4(0, 0, 0, 0), vl = make_uint4(0, 0, 0, 0);
      if (ir >= 0 && ir < 13 && ic >= 0 && ic < 13) {
        const size_t g = ((size_t)b * 169 + ir * 13 + ic) * C_in + cc * 32 + kg * 8;
        vh = *reinterpret_cast<const uint4*>(xh + g);
        vl = *reinterpret_cast<const uint4*>(xl + g);
      }
      *reinterpret_cast<uint4*>(xt_h + sp * 40 + kg * 8) = vh;
      *reinterpret_cast<uint4*>(xt_l + sp * 40 + kg * 8) = vl;
    }
    __syncthreads();
#pragma unroll
    for (int p = 0; p < 9; ++p) {
      const int kh = p / 3, kw = p % 3;
      const size_t wg = ((size_t)(co0 + fr) * 9 + p) * C_in + cc * 32 + k0;
      const bf16x8 a_h = __builtin_bit_cast(bf16x8, *reinterpret_cast<const uint4*>(wh + wg));
      const bf16x8 a_l = __builtin_bit_cast(bf16x8, *reinterpret_cast<const uint4*>(wl + wg));
      const int poff = (kh * 15 + kw) * 40;
#pragma unroll
      for (int nt = 0; nt < 11; ++nt) {
        const bf16x8 b_h = __builtin_bit_cast(bf16x8,
            *reinterpret_cast<const uint4*>(xt_h + bofs[nt] + poff));
        const bf16x8 b_l = __builtin_bit_cast(bf16x8,
            *reinterpret_cast<const uint4*>(xt_l + bofs[nt] + poff));
        acc[nt] = __builtin_amdgcn_mfma_f32_16x16x32_bf16(a_h, b_h, acc[nt], 0, 0, 0);
        acc[nt] = __builtin_amdgcn_mfma_f32_16x16x32_bf16(a_h, b_l, acc[nt], 0, 0, 0);
        acc[nt] = __builtin_amdgcn_mfma_f32_16x16x32_bf16(a_l, b_h, acc[nt], 0, 0, 0);
      }
    }
  }
  const int co_w = co0 + fq * 4;
  const float4 bi = *reinterpret_cast<const float4*>(bias + co_w);
  const float bia[4] = {bi.x, bi.y, bi.z, bi.w};
#pragma unroll
  for (int nt = 0; nt < 11; ++nt) {
    const int n = nt * 16 + fr;
    if (n > 168) continue;
    unsigned short h[4], l[4];
#pragma unroll
    for (int r = 0; r < 4; ++r) {
      float v = fmaxf(acc[nt][r] + bia[r], 0.f);
      bf16split(v, h[r], l[r]);
    }
    const size_t g = ((size_t)b * 169 + n) * C_out + co_w;
    *reinterpret_cast<uint2*>(yh + g) =
        make_uint2((unsigned)h[0] | ((unsigned)h[1] << 16),
                   (unsigned)h[2] | ((unsigned)h[3] << 16));
    *reinterpret_cast<uint2*>(yl + g) =
        make_uint2((unsigned)l[0] | ((unsigned)l[1] << 16),
                   (unsigned)l[2] | ((unsigned)l[3] << 16));
  }
}

// ---------------- pool3: Y5 hi/lo [b][169][256] -> fp32 [b][256][6][6]
__global__ __launch_bounds__(256) void pool3_hl_kernel(
    const unsigned short* __restrict__ yh, const unsigned short* __restrict__ yl,
    float* __restrict__ out) {
  const int b = blockIdx.x;
  const int s2 = blockIdx.y;
  const int c = threadIdx.x;
  const int oh = s2 / 6, ow = s2 % 6;
  float m = -INFINITY;
#pragma unroll
  for (int kh = 0; kh < 3; ++kh)
#pragma unroll
    for (int kw = 0; kw < 3; ++kw) {
      const int si = (oh * 2 + kh) * 13 + (ow * 2 + kw);
      const size_t g = ((size_t)b * 169 + si) * 256 + c;
      m = fmaxf(m, bf2f(yh[g]) + bf2f(yl[g]));
    }
  out[((size_t)b * 256 + c) * 36 + s2] = m;
}

// ---------------- fc1/fc2: out[M,N] = relu(A[M,K] @ W[N,K]^T + bias)
// BM=64 BN=32 BK=32, 256 threads (8 tx x 32 ty), 2x4 micro -> 256 blocks.
__global__ __launch_bounds__(256) void fcgemm_kernel(
    const float* __restrict__ A, const float* __restrict__ W,
    const float* __restrict__ bias, float* __restrict__ out,
    int M, int N, int K, int relu) {
  __shared__ float As[32 * 68];
  __shared__ float Ws[32 * 36];
  const int t = threadIdx.x;
  const int tx = t % 8, ty = t / 8;
  const int M0 = blockIdx.x * 64, N0 = blockIdx.y * 32;

  float acc[2][4];
#pragma unroll
  for (int i = 0; i < 2; ++i)
#pragma unroll
    for (int j = 0; j < 4; ++j) acc[i][j] = 0.f;

  for (int k0 = 0; k0 < K; k0 += 32) {
    __syncthreads();
#pragma unroll
    for (int i = 0; i < 8; ++i) {
      const int e = t + i * 256;
      const int kk = e % 32, m = e / 32;
      As[kk * 68 + m] = A[(size_t)(M0 + m) * K + k0 + kk];
    }
#pragma unroll
    for (int i = 0; i < 4; ++i) {
      const int e = t + i * 256;
      const int kk = e % 32, n = e / 32;
      Ws[kk * 36 + n] = W[(size_t)(N0 + n) * K + k0 + kk];
    }
    __syncthreads();
#pragma unroll
    for (int kk = 0; kk < 32; ++kk) {
      const float2 av = *reinterpret_cast<const float2*>(&As[kk * 68 + ty * 2]);
      const float4 wv = *reinterpret_cast<const float4*>(&Ws[kk * 36 + tx * 4]);
      const float a_[2] = {av.x, av.y};
      const float w_[4] = {wv.x, wv.y, wv.z, wv.w};
#pragma unroll
      for (int i = 0; i < 2; ++i)
#pragma unroll
        for (int j = 0; j < 4; ++j) acc[i][j] = fmaf(a_[i], w_[j], acc[i][j]);
    }
  }
#pragma unroll
  for (int i = 0; i < 2; ++i) {
    const int m = M0 + ty * 2 + i;
#pragma unroll
    for (int j = 0; j < 4; ++j) {
      const int n = N0 + tx * 4 + j;
      float r = acc[i][j] + bias[n];
      if (relu) r = fmaxf(r, 0.f);
      out[(size_t)m * N + n] = r;
    }
  }
}

// ---------------- fc3: logits[128,10]
__global__ __launch_bounds__(256) void fc3_kernel(
    const float* __restrict__ A, const float* __restrict__ W,
    const float* __restrict__ bias, float* __restrict__ out) {
  __shared__ float red[256];
  const int b = blockIdx.x;
  const int t = threadIdx.x;
  float acc[10];
#pragma unroll
  for (int n = 0; n < 10; ++n) acc[n] = 0.f;
  const float* a = A + (size_t)b * 4096;
  for (int k = t; k < 4096; k += 256) {
    const float av = a[k];
#pragma unroll
    for (int n = 0; n < 10; ++n) acc[n] = fmaf(av, W[n * 4096 + k], acc[n]);
  }
  for (int n = 0; n < 10; ++n) {
    red[t] = acc[n];
    __syncthreads();
    for (int off = 128; off > 0; off >>= 1) {
      if (t < off) red[t] += red[t + off];
      __syncthreads();
    }
    if (t == 0) out[b * 10 + n] = red[0] + bias[n];
    __syncthreads();
  }
}

// ---------------- post
__global__ void post_kernel(const float* __restrict__ logits,
                            const float* __restrict__ unif,
                            const float* __restrict__ noise,
                            float* __restrict__ out) {
  const int b = blockIdx.x * blockDim.x + threadIdx.x;
  if (b >= 128) return;
  float lg[10];
#pragma unroll
  for (int j = 0; j < 10; ++j) lg[j] = logits[b * 10 + j];
  float m = lg[0];
  int idx = 0;
#pragma unroll
  for (int j = 1; j < 10; ++j) {
    if (lg[j] > m) { m = lg[j]; idx = j; }
  }
  float v[10];
#pragma unroll
  for (int j = 0; j < 10; ++j)
    v[j] = ((j == idx) ? lg[j] : unif[b * 10 + j] * m) + noise[b * 10 + j];
  float mx = v[0];
#pragma unroll
  for (int j = 1; j < 10; ++j) mx = fmaxf(mx, v[j]);
  float sum = 0.f;
#pragma unroll
  for (int j = 0; j < 10; ++j) { v[j] = expf(v[j] - mx); sum += v[j]; }
  const float inv = 1.f / sum;
#pragma unroll
  for (int j = 0; j < 10; ++j) out[b * 10 + j] = v[j] * inv;
}

// ---------------------------------------------------------------------------
extern "C" void kernel_launch(void* const* d_in, const int* in_sizes, int n_in,
                              void* d_out, int out_size, void* d_ws, size_t ws_size,
                              hipStream_t stream) {
  const float* x     = (const float*)d_in[0];
  const float* w1    = (const float*)d_in[1];
  const float* b1    = (const float*)d_in[2];
  const float* w2    = (const float*)d_in[3];
  const float* b2    = (const float*)d_in[4];
  const float* w3    = (const float*)d_in[5];
  const float* b3    = (const float*)d_in[6];
  const float* w4    = (const float*)d_in[7];
  const float* b4    = (const float*)d_in[8];
  const float* w5    = (const float*)d_in[9];
  const float* b5    = (const float*)d_in[10];
  const float* fc1_w = (const float*)d_in[11];
  const float* fc1_b = (const float*)d_in[12];
  const float* fc2_w = (const float*)d_in[13];
  const float* fc2_b = (const float*)d_in[14];
  const float* fc3_w = (const float*)d_in[15];
  const float* fc3_b = (const float*)d_in[16];
  const float* unif  = (const float*)d_in[17];
  const float* noise = (const float*)d_in[18];
  float* out = (float*)d_out;

  char* W = (char*)d_ws;
#define FP(off) ((float*)(W + (off)))
#define US(off) ((unsigned short*)(W + (off)))

  // conv1 -> fp32 [128,64,57,57] at 0
  conv1_kernel<<<dim3(13, 128), 256, 0, stream>>>(x, w1, b1, FP(0));
  // pool1 -> fp32 [128,64,28,28]
  maxpool_kernel<<<2048, 256, 0, stream>>>(FP(0), FP(OFF_POOL1), 128 * 64, 57, 57, 28, 28);
  // pool1 -> X2 hi/lo [b][784][64]   (conv1out dead)
  x2convert_kernel<<<392, 256, 0, stream>>>(FP(OFF_POOL1), US(OFF_X2H), US(OFF_X2L));
  // weight transforms
  wtrans_hl_kernel<<<512, 256, 0, stream>>>(w2, US(OFF_WT2H), US(OFF_WT2L), 64, 25, 192);
  wtrans_hl_kernel<<<512, 256, 0, stream>>>(w3, US(OFF_WT3H), US(OFF_WT3L), 192, 9, 384);
  wtrans_hl_kernel<<<512, 256, 0, stream>>>(w4, US(OFF_WT4H), US(OFF_WT4L), 384, 9, 256);
  wtrans_hl_kernel<<<512, 256, 0, stream>>>(w5, US(OFF_WT5H), US(OFF_WT5L), 256, 9, 256);
  // conv2 -> Y2 hi/lo [b][784][192]  (pool1 dead)
  conv2_mfma_kernel<<<dim3(128, 4, 3), 256, 0, stream>>>(
      US(OFF_X2H), US(OFF_X2L), US(OFF_WT2H), US(OFF_WT2L), b2,
      US(OFF_Y2H), US(OFF_Y2L));
  // pool2 -> X3 hi/lo [b][169][192]
  pool2_hl_kernel<<<dim3(128, 13), 192, 0, stream>>>(
      US(OFF_Y2H), US(OFF_Y2L), US(OFF_X3H), US(OFF_X3L));
  // conv3 -> Y3 [b][169][384]  (Y2 dead)
  conv13_mfma_kernel<<<dim3(128, 6), 256, 0, stream>>>(
      US(OFF_X3H), US(OFF_X3L), US(OFF_WT3H), US(OFF_WT3L), b3,
      US(OFF_Y3H), US(OFF_Y3L), 192, 384);
  // conv4 -> Y4 [b][169][256]
  conv13_mfma_kernel<<<dim3(128, 4), 256, 0, stream>>>(
      US(OFF_Y3H), US(OFF_Y3L), US(OFF_WT4H), US(OFF_WT4L), b4,
      US(OFF_Y4H), US(OFF_Y4L), 384, 256);
  // conv5 -> Y5 [b][169][256]  (X3 dead)
  conv13_mfma_kernel<<<dim3(128, 4), 256, 0, stream>>>(
      US(OFF_Y4H), US(OFF_Y4L), US(OFF_WT5H), US(OFF_WT5L), b5,
      US(OFF_Y5H), US(OFF_Y5L), 256, 256);
  // pool3 -> P3 fp32 [128][9216]
  pool3_hl_kernel<<<dim3(128, 36), 256, 0, stream>>>(US(OFF_Y5H), US(OFF_Y5L), FP(OFF_P3));
  // classifier
  fcgemm_kernel<<<dim3(2, 128), 256, 0, stream>>>(FP(OFF_P3), fc1_w, fc1_b, FP(OFF_FC1), 128, 4096, 9216, 1);
  fcgemm_kernel<<<dim3(2, 128), 256, 0, stream>>>(FP(OFF_FC1), fc2_w, fc2_b, FP(OFF_FC2), 128, 4096, 4096, 1);
  fc3_kernel<<<128, 256, 0, stream>>>(FP(OFF_FC2), fc3_w, fc3_b, FP(OFF_LOG));
  post_kernel<<<1, 128, 0, stream>>>(FP(OFF_LOG), unif, noise, out);
}

// Round 6
// 894.454 us; speedup vs baseline: 14.5443x; 1.4558x over previous
//
#include <hip/hip_runtime.h>
#include <math.h>

// ---------------------------------------------------------------------------
// AlexNet forward, batch 128.
// Round 5: fc1/fc2 -> streaming MFMA with in-register fp32->bf16 hi/lo split
// (weights never converted in memory: read fp32, split in regs, x3 MFMA).
// K split 16-way -> 512 blocks; fp32 partials + reduce(bias,relu,transpose).
//
// Workspace layout (bytes):
//   conv1out fp32 [0,106.5M) -> pool1 fp32 [106.46M,132.15M)
//   X2 hi/lo [0,25.69M)   wt2/3/4/5 hi/lo [25.69M,35.47M)
//   Y2 hi/lo [36M,113.07M)   X3 hi/lo [113.1M,129.71M)
//   Y3 [36M,69.23M)  Y4 [70M,92.15M)  Y5 [93M,115.15M)
//   P3 [0,4.72M)  FC1 [5M,7.1M)  FC2 [8M,10.1M)  LOG [11M)
//   PART [40M,73.6M)  (fc partials, conv regions dead by then)
// ---------------------------------------------------------------------------

typedef __attribute__((ext_vector_type(4))) float  f32x4;
typedef __attribute__((ext_vector_type(8))) short  bf16x8;

#define OFF_POOL1    106463232ull
#define OFF_X2H      0ull
#define OFF_X2L      12845056ull
#define OFF_WT2H     25690112ull
#define OFF_WT2L     26304512ull
#define OFF_WT3H     26918912ull
#define OFF_WT3L     28246016ull
#define OFF_WT4H     29573120ull
#define OFF_WT4L     31342592ull
#define OFF_WT5H     33112064ull
#define OFF_WT5L     34291712ull
#define OFF_Y2H      36000000ull
#define OFF_Y2L      74535168ull
#define OFF_X3H      113100000ull
#define OFF_X3L      121406688ull
#define OFF_Y3H      36000000ull
#define OFF_Y3L      52613376ull
#define OFF_Y4H      70000000ull
#define OFF_Y4L      81075584ull
#define OFF_Y5H      93000000ull
#define OFF_Y5L      104075584ull
#define OFF_P3       0ull
#define OFF_FC1      5000000ull
#define OFF_FC2      8000000ull
#define OFF_LOG      11000000ull
#define OFF_PART     40000000ull

__device__ inline void bf16split(float v, unsigned short& h, unsigned short& l) {
  unsigned u = __builtin_bit_cast(unsigned, v);
  unsigned hb = (u + 0x7fffu + ((u >> 16) & 1u)) >> 16;        // RNE to bf16
  h = (unsigned short)hb;
  float hf = __builtin_bit_cast(float, hb << 16);
  float r = v - hf;
  unsigned u2 = __builtin_bit_cast(unsigned, r);
  l = (unsigned short)((u2 + 0x7fffu + ((u2 >> 16) & 1u)) >> 16);
}
// trunc-hi split: hi exact truncation (1 op), lo = RNE(v - hi) (exact residual)
__device__ inline void bf16split_fast(float v, unsigned short& h, unsigned short& l) {
  unsigned u = __builtin_bit_cast(unsigned, v);
  h = (unsigned short)(u >> 16);
  float r = v - __builtin_bit_cast(float, u & 0xFFFF0000u);
  unsigned u2 = __builtin_bit_cast(unsigned, r);
  l = (unsigned short)((u2 + 0x7fffu + ((u2 >> 16) & 1u)) >> 16);
}
__device__ inline float bf2f(unsigned short h) {
  return __builtin_bit_cast(float, ((unsigned)h) << 16);
}

// ---------------- conv1: x[128,3,224,224] -> y1[128,64,57,57], k3 s4 p2, relu
__global__ __launch_bounds__(256) void conv1_kernel(
    const float* __restrict__ x, const float* __restrict__ w,
    const float* __restrict__ bias, float* __restrict__ out) {
  const int b = blockIdx.y;
  const int s = blockIdx.x * 256 + threadIdx.x;
  if (s >= 57 * 57) return;
  const int oh = s / 57, ow = s % 57;
  float iv[27];
#pragma unroll
  for (int ci = 0; ci < 3; ++ci)
#pragma unroll
    for (int kh = 0; kh < 3; ++kh)
#pragma unroll
      for (int kw = 0; kw < 3; ++kw) {
        const int ih = oh * 4 - 2 + kh;
        const int iw = ow * 4 - 2 + kw;
        float v = 0.f;
        if (ih >= 0 && ih < 224 && iw >= 0 && iw < 224)
          v = x[(((size_t)b * 3 + ci) * 224 + ih) * 224 + iw];
        iv[ci * 9 + kh * 3 + kw] = v;
      }
  for (int co = 0; co < 64; ++co) {
    float a = bias[co];
#pragma unroll
    for (int p = 0; p < 27; ++p) a = fmaf(w[co * 27 + p], iv[p], a);
    out[((size_t)b * 64 + co) * 3249 + s] = fmaxf(a, 0.f);
  }
}

// ---------------- maxpool 3x3 s2 fp32 NCHW (pool1 only)
__global__ void maxpool_kernel(const float* __restrict__ in, float* __restrict__ out,
                               int BC, int H, int W, int OH, int OW) {
  const int total = BC * OH * OW;
  for (int idx = blockIdx.x * blockDim.x + threadIdx.x; idx < total;
       idx += gridDim.x * blockDim.x) {
    const int ow = idx % OW;
    int tmp = idx / OW;
    const int oh = tmp % OH;
    const int bc = tmp / OH;
    const float* p = in + (size_t)bc * H * W + (size_t)(oh * 2) * W + ow * 2;
    float m = -INFINITY;
#pragma unroll
    for (int kh = 0; kh < 3; ++kh)
#pragma unroll
      for (int kw = 0; kw < 3; ++kw) m = fmaxf(m, p[kh * W + kw]);
    out[idx] = m;
  }
}

// ---------------- pool1 fp32 [b][64][28][28] -> X2 hi/lo bf16 [b][784][64]
__global__ __launch_bounds__(256) void x2convert_kernel(
    const float* __restrict__ in, unsigned short* __restrict__ xh,
    unsigned short* __restrict__ xl) {
  const int tid = blockIdx.x * 256 + threadIdx.x;
  if (tid >= 128 * 784) return;
  const int b = tid / 784, s = tid % 784;
  for (int cg = 0; cg < 16; ++cg) {
    unsigned short h[4], l[4];
#pragma unroll
    for (int j = 0; j < 4; ++j) {
      const float v = in[((size_t)b * 64 + cg * 4 + j) * 784 + s];
      bf16split(v, h[j], l[j]);
    }
    const size_t g = ((size_t)b * 784 + s) * 64 + cg * 4;
    *reinterpret_cast<uint2*>(xh + g) =
        make_uint2((unsigned)h[0] | ((unsigned)h[1] << 16),
                   (unsigned)h[2] | ((unsigned)h[3] << 16));
    *reinterpret_cast<uint2*>(xl + g) =
        make_uint2((unsigned)l[0] | ((unsigned)l[1] << 16),
                   (unsigned)l[2] | ((unsigned)l[3] << 16));
  }
}

// ---------------- weight transform: w[co][ci][P] fp32 -> wh/wl [co][p][ci] bf16
__global__ void wtrans_hl_kernel(const float* __restrict__ w,
                                 unsigned short* __restrict__ wh,
                                 unsigned short* __restrict__ wl,
                                 int C_in, int P, int C_out) {
  const int total = C_out * P * C_in;
  for (int e = blockIdx.x * blockDim.x + threadIdx.x; e < total;
       e += gridDim.x * blockDim.x) {
    const int ci = e % C_in;
    const int p = (e / C_in) % P;
    const int co = e / (C_in * P);
    const float v = w[((size_t)co * C_in + ci) * P + p];
    unsigned short h, l;
    bf16split(v, h, l);
    wh[e] = h; wl[e] = l;
  }
}

// ---------------- conv2 MFMA (validated round 4)
__global__ __launch_bounds__(256, 2) void conv2_mfma_kernel(
    const unsigned short* __restrict__ xh, const unsigned short* __restrict__ xl,
    const unsigned short* __restrict__ wh, const unsigned short* __restrict__ wl,
    const float* __restrict__ bias,
    unsigned short* __restrict__ yh, unsigned short* __restrict__ yl) {
  __shared__ unsigned short xt_h[352 * 40];
  __shared__ unsigned short xt_l[352 * 40];
  const int t = threadIdx.x;
  const int lane = t & 63, wv = t >> 6;
  const int b = blockIdx.x;
  const int rg = blockIdx.y;
  const int cg = blockIdx.z;
  const int fr = lane & 15, fq = lane >> 4;
  const int k0 = fq * 8;

  int bofs[4];
#pragma unroll
  for (int ti = 0; ti < 4; ++ti) {
    const int tile = ti * 4 + wv;
    int n = tile * 16 + fr;
    if (tile > 12 || n > 195) n = 195;
    const int r = n / 28, c = n % 28;
    bofs[ti] = (r * 32 + c) * 40 + k0;
  }

  f32x4 acc[4][4];
#pragma unroll
  for (int i = 0; i < 4; ++i)
#pragma unroll
    for (int j = 0; j < 4; ++j) acc[i][j] = (f32x4){0.f, 0.f, 0.f, 0.f};

  for (int cc = 0; cc < 2; ++cc) {
    __syncthreads();
    for (int e = t; e < 1408; e += 256) {
      const int sp = e >> 2, kg = e & 3;
      const int hr = sp >> 5, hc = sp & 31;
      const int ih = rg * 7 + hr - 2, ic = hc - 2;
      uint4 vh = make_uint4(0, 0, 0, 0), vl = make_uint4(0, 0, 0, 0);
      if (ih >= 0 && ih < 28 && ic >= 0 && ic < 28) {
        const size_t g = ((size_t)b * 784 + ih * 28 + ic) * 64 + cc * 32 + kg * 8;
        vh = *reinterpret_cast<const uint4*>(xh + g);
        vl = *reinterpret_cast<const uint4*>(xl + g);
      }
      *reinterpret_cast<uint4*>(xt_h + sp * 40 + kg * 8) = vh;
      *reinterpret_cast<uint4*>(xt_l + sp * 40 + kg * 8) = vl;
    }
    __syncthreads();
#pragma unroll 5
    for (int p = 0; p < 25; ++p) {
      const int kh = p / 5, kw = p % 5;
      bf16x8 a_h[4], a_l[4];
#pragma unroll
      for (int cot = 0; cot < 4; ++cot) {
        const size_t wg = ((size_t)(cg * 64 + cot * 16 + fr) * 25 + p) * 64 + cc * 32 + k0;
        a_h[cot] = __builtin_bit_cast(bf16x8, *reinterpret_cast<const uint4*>(wh + wg));
        a_l[cot] = __builtin_bit_cast(bf16x8, *reinterpret_cast<const uint4*>(wl + wg));
      }
      const int poff = (kh * 32 + kw) * 40;
#pragma unroll
      for (int ti = 0; ti < 4; ++ti) {
        if (ti * 4 + wv <= 12) {
          const bf16x8 b_h = __builtin_bit_cast(bf16x8,
              *reinterpret_cast<const uint4*>(xt_h + bofs[ti] + poff));
          const bf16x8 b_l = __builtin_bit_cast(bf16x8,
              *reinterpret_cast<const uint4*>(xt_l + bofs[ti] + poff));
#pragma unroll
          for (int cot = 0; cot < 4; ++cot) {
            acc[ti][cot] = __builtin_amdgcn_mfma_f32_16x16x32_bf16(a_h[cot], b_h, acc[ti][cot], 0, 0, 0);
            acc[ti][cot] = __builtin_amdgcn_mfma_f32_16x16x32_bf16(a_h[cot], b_l, acc[ti][cot], 0, 0, 0);
            acc[ti][cot] = __builtin_amdgcn_mfma_f32_16x16x32_bf16(a_l[cot], b_h, acc[ti][cot], 0, 0, 0);
          }
        }
      }
    }
  }
#pragma unroll
  for (int cot = 0; cot < 4; ++cot) {
    const int co = cg * 64 + cot * 16 + fq * 4;
    const float4 bi = *reinterpret_cast<const float4*>(bias + co);
    const float bia[4] = {bi.x, bi.y, bi.z, bi.w};
#pragma unroll
    for (int ti = 0; ti < 4; ++ti) {
      const int tile = ti * 4 + wv;
      if (tile > 12) continue;
      const int n = tile * 16 + fr;
      if (n > 195) continue;
      const int oh = rg * 7 + n / 28, ow = n % 28;
      unsigned short h[4], l[4];
#pragma unroll
      for (int r = 0; r < 4; ++r) {
        const float v = fmaxf(acc[ti][cot][r] + bia[r], 0.f);
        bf16split(v, h[r], l[r]);
      }
      const size_t g = ((size_t)b * 784 + oh * 28 + ow) * 192 + co;
      *reinterpret_cast<uint2*>(yh + g) =
          make_uint2((unsigned)h[0] | ((unsigned)h[1] << 16),
                     (unsigned)h[2] | ((unsigned)h[3] << 16));
      *reinterpret_cast<uint2*>(yl + g) =
          make_uint2((unsigned)l[0] | ((unsigned)l[1] << 16),
                     (unsigned)l[2] | ((unsigned)l[3] << 16));
    }
  }
}

// ---------------- pool2: Y2 hi/lo [b][784][192] -> X3 hi/lo [b][169][192]
__global__ __launch_bounds__(192) void pool2_hl_kernel(
    const unsigned short* __restrict__ yh, const unsigned short* __restrict__ yl,
    unsigned short* __restrict__ xh, unsigned short* __restrict__ xl) {
  const int b = blockIdx.x, oh = blockIdx.y;
  const int c = threadIdx.x;
  for (int ow = 0; ow < 13; ++ow) {
    float m = -INFINITY;
#pragma unroll
    for (int kh = 0; kh < 3; ++kh)
#pragma unroll
      for (int kw = 0; kw < 3; ++kw) {
        const int s = (oh * 2 + kh) * 28 + (ow * 2 + kw);
        const size_t g = ((size_t)b * 784 + s) * 192 + c;
        m = fmaxf(m, bf2f(yh[g]) + bf2f(yl[g]));
      }
    unsigned short h, l;
    bf16split(m, h, l);
    const size_t gd = ((size_t)b * 169 + oh * 13 + ow) * 192 + c;
    xh[gd] = h; xl[gd] = l;
  }
}

// ---------------- conv3/4/5 MFMA (validated round 3)
__global__ __launch_bounds__(256, 4) void conv13_mfma_kernel(
    const unsigned short* __restrict__ xh, const unsigned short* __restrict__ xl,
    const unsigned short* __restrict__ wh, const unsigned short* __restrict__ wl,
    const float* __restrict__ bias,
    unsigned short* __restrict__ yh, unsigned short* __restrict__ yl,
    int C_in, int C_out) {
  __shared__ unsigned short xt_h[225 * 40];
  __shared__ unsigned short xt_l[225 * 40];
  const int t = threadIdx.x;
  const int lane = t & 63;
  const int wv = t >> 6;
  const int b = blockIdx.x;
  const int co0 = blockIdx.y * 64 + wv * 16;
  const int fr = lane & 15;
  const int fq = lane >> 4;
  const int k0 = fq * 8;

  int bofs[11];
#pragma unroll
  for (int nt = 0; nt < 11; ++nt) {
    int n = nt * 16 + fr;
    if (n > 168) n = 168;
    const int oh = n / 13, ow = n % 13;
    bofs[nt] = (oh * 15 + ow) * 40 + k0;
  }

  f32x4 acc[11];
#pragma unroll
  for (int nt = 0; nt < 11; ++nt) acc[nt] = (f32x4){0.f, 0.f, 0.f, 0.f};

  const int nchunk = C_in >> 5;
  for (int cc = 0; cc < nchunk; ++cc) {
    __syncthreads();
    for (int e = t; e < 900; e += 256) {
      const int sp = e >> 2, kg = e & 3;
      const int r = sp / 15, c = sp % 15;
      const int ir = r - 1, ic = c - 1;
      uint4 vh = make_uint4(0, 0, 0, 0), vl = make_uint4(0, 0, 0, 0);
      if (ir >= 0 && ir < 13 && ic >= 0 && ic < 13) {
        const size_t g = ((size_t)b * 169 + ir * 13 + ic) * C_in + cc * 32 + kg * 8;
        vh = *reinterpret_cast<const uint4*>(xh + g);
        vl = *reinterpret_cast<const uint4*>(xl + g);
      }
      *reinterpret_cast<uint4*>(xt_h + sp * 40 + kg * 8) = vh;
      *reinterpret_cast<uint4*>(xt_l + sp * 40 + kg * 8) = vl;
    }
    __syncthreads();
#pragma unroll
    for (int p = 0; p < 9; ++p) {
      const int kh = p / 3, kw = p % 3;
      const size_t wg = ((size_t)(co0 + fr) * 9 + p) * C_in + cc * 32 + k0;
      const bf16x8 a_h = __builtin_bit_cast(bf16x8, *reinterpret_cast<const uint4*>(wh + wg));
      const bf16x8 a_l = __builtin_bit_cast(bf16x8, *reinterpret_cast<const uint4*>(wl + wg));
      const int poff = (kh * 15 + kw) * 40;
#pragma unroll
      for (int nt = 0; nt < 11; ++nt) {
        const bf16x8 b_h = __builtin_bit_cast(bf16x8,
            *reinterpret_cast<const uint4*>(xt_h + bofs[nt] + poff));
        const bf16x8 b_l = __builtin_bit_cast(bf16x8,
            *reinterpret_cast<const uint4*>(xt_l + bofs[nt] + poff));
        acc[nt] = __builtin_amdgcn_mfma_f32_16x16x32_bf16(a_h, b_h, acc[nt], 0, 0, 0);
        acc[nt] = __builtin_amdgcn_mfma_f32_16x16x32_bf16(a_h, b_l, acc[nt], 0, 0, 0);
        acc[nt] = __builtin_amdgcn_mfma_f32_16x16x32_bf16(a_l, b_h, acc[nt], 0, 0, 0);
      }
    }
  }
  const int co_w = co0 + fq * 4;
  const float4 bi = *reinterpret_cast<const float4*>(bias + co_w);
  const float bia[4] = {bi.x, bi.y, bi.z, bi.w};
#pragma unroll
  for (int nt = 0; nt < 11; ++nt) {
    const int n = nt * 16 + fr;
    if (n > 168) continue;
    unsigned short h[4], l[4];
#pragma unroll
    for (int r = 0; r < 4; ++r) {
      float v = fmaxf(acc[nt][r] + bia[r], 0.f);
      bf16split(v, h[r], l[r]);
    }
    const size_t g = ((size_t)b * 169 + n) * C_out + co_w;
    *reinterpret_cast<uint2*>(yh + g) =
        make_uint2((unsigned)h[0] | ((unsigned)h[1] << 16),
                   (unsigned)h[2] | ((unsigned)h[3] << 16));
    *reinterpret_cast<uint2*>(yl + g) =
        make_uint2((unsigned)l[0] | ((unsigned)l[1] << 16),
                   (unsigned)l[2] | ((unsigned)l[3] << 16));
  }
}

// ---------------- pool3: Y5 hi/lo [b][169][256] -> fp32 [b][256][6][6]
__global__ __launch_bounds__(256) void pool3_hl_kernel(
    const unsigned short* __restrict__ yh, const unsigned short* __restrict__ yl,
    float* __restrict__ out) {
  const int b = blockIdx.x;
  const int s2 = blockIdx.y;
  const int c = threadIdx.x;
  const int oh = s2 / 6, ow = s2 % 6;
  float m = -INFINITY;
#pragma unroll
  for (int kh = 0; kh < 3; ++kh)
#pragma unroll
    for (int kw = 0; kw < 3; ++kw) {
      const int si = (oh * 2 + kh) * 13 + (ow * 2 + kw);
      const size_t g = ((size_t)b * 169 + si) * 256 + c;
      m = fmaxf(m, bf2f(yh[g]) + bf2f(yl[g]));
    }
  out[((size_t)b * 256 + c) * 36 + s2] = m;
}

// ---------------- fc1/fc2 MFMA: act fp32 [128][K], W fp32 [Cout][K]
// -> partials fp32 [KS][Cout][128]. Grid (Cout/128, KS), 256 thr = 4 waves,
// wave = 32 rows (2 M-tiles) x 8 n-tiles (full batch). Weights split to
// bf16 hi/lo IN REGISTERS (no memory conversion); act staged hi/lo in LDS.
__global__ __launch_bounds__(256, 2) void fc_mfma_kernel(
    const float* __restrict__ act, const float* __restrict__ Wm,
    float* __restrict__ part, int K, int kchunk, int Cout) {
  __shared__ unsigned short ah[128 * 40];
  __shared__ unsigned short al[128 * 40];
  const int t = threadIdx.x;
  const int lane = t & 63, wv = t >> 6;
  const int m0 = blockIdx.x * 128 + wv * 32;
  const int kb = blockIdx.y * kchunk;
  const int fr = lane & 15, fq = lane >> 4;

  f32x4 acc[2][8];
#pragma unroll
  for (int i = 0; i < 2; ++i)
#pragma unroll
    for (int j = 0; j < 8; ++j) acc[i][j] = (f32x4){0.f, 0.f, 0.f, 0.f};

  for (int kc = kb; kc < kb + kchunk; kc += 32) {
    __syncthreads();
    // stage act[0..128)[kc..kc+32) as hi/lo bf16, LDS row stride 40 shorts
#pragma unroll
    for (int i = 0; i < 4; ++i) {
      const int u = t + i * 256;
      const int n = u >> 3, j = u & 7;
      const float4 v = *reinterpret_cast<const float4*>(act + (size_t)n * K + kc + j * 4);
      const float vv[4] = {v.x, v.y, v.z, v.w};
      unsigned short h[4], l[4];
#pragma unroll
      for (int q = 0; q < 4; ++q) bf16split_fast(vv[q], h[q], l[q]);
      *reinterpret_cast<uint2*>(ah + n * 40 + j * 4) =
          make_uint2((unsigned)h[0] | ((unsigned)h[1] << 16),
                     (unsigned)h[2] | ((unsigned)h[3] << 16));
      *reinterpret_cast<uint2*>(al + n * 40 + j * 4) =
          make_uint2((unsigned)l[0] | ((unsigned)l[1] << 16),
                     (unsigned)l[2] | ((unsigned)l[3] << 16));
    }
    __syncthreads();
    // A-frags: stream W fp32, split in regs
    bf16x8 a_h[2], a_l[2];
#pragma unroll
    for (int mt = 0; mt < 2; ++mt) {
      const float* wp = Wm + (size_t)(m0 + mt * 16 + fr) * K + kc + fq * 8;
      const float4 w0 = *reinterpret_cast<const float4*>(wp);
      const float4 w1 = *reinterpret_cast<const float4*>(wp + 4);
      const float ws[8] = {w0.x, w0.y, w0.z, w0.w, w1.x, w1.y, w1.z, w1.w};
#pragma unroll
      for (int q = 0; q < 8; ++q) {
        unsigned short h, l;
        bf16split_fast(ws[q], h, l);
        a_h[mt][q] = (short)h;
        a_l[mt][q] = (short)l;
      }
    }
#pragma unroll
    for (int nt = 0; nt < 8; ++nt) {
      const bf16x8 b_h = __builtin_bit_cast(bf16x8,
          *reinterpret_cast<const uint4*>(ah + (nt * 16 + fr) * 40 + fq * 8));
      const bf16x8 b_l = __builtin_bit_cast(bf16x8,
          *reinterpret_cast<const uint4*>(al + (nt * 16 + fr) * 40 + fq * 8));
#pragma unroll
      for (int mt = 0; mt < 2; ++mt) {
        acc[mt][nt] = __builtin_amdgcn_mfma_f32_16x16x32_bf16(a_h[mt], b_h, acc[mt][nt], 0, 0, 0);
        acc[mt][nt] = __builtin_amdgcn_mfma_f32_16x16x32_bf16(a_h[mt], b_l, acc[mt][nt], 0, 0, 0);
        acc[mt][nt] = __builtin_amdgcn_mfma_f32_16x16x32_bf16(a_l[mt], b_h, acc[mt][nt], 0, 0, 0);
      }
    }
  }
  // partial write: part[(ks*Cout + m)*128 + n]; D: col=fr (n), row=fq*4+r
  const size_t base = (size_t)blockIdx.y * Cout * 128;
#pragma unroll
  for (int mt = 0; mt < 2; ++mt) {
#pragma unroll
    for (int nt = 0; nt < 8; ++nt) {
#pragma unroll
      for (int r = 0; r < 4; ++r) {
        const int m = m0 + mt * 16 + fq * 4 + r;
        const int n = nt * 16 + fr;
        part[base + (size_t)m * 128 + n] = acc[mt][nt][r];
      }
    }
  }
}

// ---------------- fc reduce: sum KS partials, +bias, relu, transpose to [n][Cout]
__global__ __launch_bounds__(256) void fc_reduce_kernel(
    const float* __restrict__ part, const float* __restrict__ bias,
    float* __restrict__ out, int Cout, int KS, int relu) {
  const int g = blockIdx.x * 256 + threadIdx.x;
  if (g >= Cout * 128) return;
  const int n = g & 127, m = g >> 7;
  float s = 0.f;
  for (int ks = 0; ks < KS; ++ks)
    s += part[(size_t)ks * Cout * 128 + (size_t)m * 128 + n];
  s += bias[m];
  if (relu) s = fmaxf(s, 0.f);
  out[(size_t)n * Cout + m] = s;
}

// ---------------- fc3: logits[128,10]
__global__ __launch_bounds__(256) void fc3_kernel(
    const float* __restrict__ A, const float* __restrict__ W,
    const float* __restrict__ bias, float* __restrict__ out) {
  __shared__ float red[256];
  const int b = blockIdx.x;
  const int t = threadIdx.x;
  float acc[10];
#pragma unroll
  for (int n = 0; n < 10; ++n) acc[n] = 0.f;
  const float* a = A + (size_t)b * 4096;
  for (int k = t; k < 4096; k += 256) {
    const float av = a[k];
#pragma unroll
    for (int n = 0; n < 10; ++n) acc[n] = fmaf(av, W[n * 4096 + k], acc[n]);
  }
  for (int n = 0; n < 10; ++n) {
    red[t] = acc[n];
    __syncthreads();
    for (int off = 128; off > 0; off >>= 1) {
      if (t < off) red[t] += red[t + off];
      __syncthreads();
    }
    if (t == 0) out[b * 10 + n] = red[0] + bias[n];
    __syncthreads();
  }
}

// ---------------- post
__global__ void post_kernel(const float* __restrict__ logits,
                            const float* __restrict__ unif,
                            const float* __restrict__ noise,
                            float* __restrict__ out) {
  const int b = blockIdx.x * blockDim.x + threadIdx.x;
  if (b >= 128) return;
  float lg[10];
#pragma unroll
  for (int j = 0; j < 10; ++j) lg[j] = logits[b * 10 + j];
  float m = lg[0];
  int idx = 0;
#pragma unroll
  for (int j = 1; j < 10; ++j) {
    if (lg[j] > m) { m = lg[j]; idx = j; }
  }
  float v[10];
#pragma unroll
  for (int j = 0; j < 10; ++j)
    v[j] = ((j == idx) ? lg[j] : unif[b * 10 + j] * m) + noise[b * 10 + j];
  float mx = v[0];
#pragma unroll
  for (int j = 1; j < 10; ++j) mx = fmaxf(mx, v[j]);
  float sum = 0.f;
#pragma unroll
  for (int j = 0; j < 10; ++j) { v[j] = expf(v[j] - mx); sum += v[j]; }
  const float inv = 1.f / sum;
#pragma unroll
  for (int j = 0; j < 10; ++j) out[b * 10 + j] = v[j] * inv;
}

// ---------------------------------------------------------------------------
extern "C" void kernel_launch(void* const* d_in, const int* in_sizes, int n_in,
                              void* d_out, int out_size, void* d_ws, size_t ws_size,
                              hipStream_t stream) {
  const float* x     = (const float*)d_in[0];
  const float* w1    = (const float*)d_in[1];
  const float* b1    = (const float*)d_in[2];
  const float* w2    = (const float*)d_in[3];
  const float* b2    = (const float*)d_in[4];
  const float* w3    = (const float*)d_in[5];
  const float* b3    = (const float*)d_in[6];
  const float* w4    = (const float*)d_in[7];
  const float* b4    = (const float*)d_in[8];
  const float* w5    = (const float*)d_in[9];
  const float* b5    = (const float*)d_in[10];
  const float* fc1_w = (const float*)d_in[11];
  const float* fc1_b = (const float*)d_in[12];
  const float* fc2_w = (const float*)d_in[13];
  const float* fc2_b = (const float*)d_in[14];
  const float* fc3_w = (const float*)d_in[15];
  const float* fc3_b = (const float*)d_in[16];
  const float* unif  = (const float*)d_in[17];
  const float* noise = (const float*)d_in[18];
  float* out = (float*)d_out;

  char* W = (char*)d_ws;
#define FP(off) ((float*)(W + (off)))
#define US(off) ((unsigned short*)(W + (off)))

  // conv1 -> fp32 [128,64,57,57]
  conv1_kernel<<<dim3(13, 128), 256, 0, stream>>>(x, w1, b1, FP(0));
  // pool1 -> fp32 [128,64,28,28]
  maxpool_kernel<<<2048, 256, 0, stream>>>(FP(0), FP(OFF_POOL1), 128 * 64, 57, 57, 28, 28);
  // pool1 -> X2 hi/lo [b][784][64]
  x2convert_kernel<<<392, 256, 0, stream>>>(FP(OFF_POOL1), US(OFF_X2H), US(OFF_X2L));
  // weight transforms
  wtrans_hl_kernel<<<512, 256, 0, stream>>>(w2, US(OFF_WT2H), US(OFF_WT2L), 64, 25, 192);
  wtrans_hl_kernel<<<512, 256, 0, stream>>>(w3, US(OFF_WT3H), US(OFF_WT3L), 192, 9, 384);
  wtrans_hl_kernel<<<512, 256, 0, stream>>>(w4, US(OFF_WT4H), US(OFF_WT4L), 384, 9, 256);
  wtrans_hl_kernel<<<512, 256, 0, stream>>>(w5, US(OFF_WT5H), US(OFF_WT5L), 256, 9, 256);
  // conv2 -> Y2 hi/lo [b][784][192]
  conv2_mfma_kernel<<<dim3(128, 4, 3), 256, 0, stream>>>(
      US(OFF_X2H), US(OFF_X2L), US(OFF_WT2H), US(OFF_WT2L), b2,
      US(OFF_Y2H), US(OFF_Y2L));
  // pool2 -> X3 hi/lo [b][169][192]
  pool2_hl_kernel<<<dim3(128, 13), 192, 0, stream>>>(
      US(OFF_Y2H), US(OFF_Y2L), US(OFF_X3H), US(OFF_X3L));
  // conv3 -> Y3 [b][169][384]
  conv13_mfma_kernel<<<dim3(128, 6), 256, 0, stream>>>(
      US(OFF_X3H), US(OFF_X3L), US(OFF_WT3H), US(OFF_WT3L), b3,
      US(OFF_Y3H), US(OFF_Y3L), 192, 384);
  // conv4 -> Y4 [b][169][256]
  conv13_mfma_kernel<<<dim3(128, 4), 256, 0, stream>>>(
      US(OFF_Y3H), US(OFF_Y3L), US(OFF_WT4H), US(OFF_WT4L), b4,
      US(OFF_Y4H), US(OFF_Y4L), 384, 256);
  // conv5 -> Y5 [b][169][256]
  conv13_mfma_kernel<<<dim3(128, 4), 256, 0, stream>>>(
      US(OFF_Y4H), US(OFF_Y4L), US(OFF_WT5H), US(OFF_WT5L), b5,
      US(OFF_Y5H), US(OFF_Y5L), 256, 256);
  // pool3 -> P3 fp32 [128][9216]
  pool3_hl_kernel<<<dim3(128, 36), 256, 0, stream>>>(US(OFF_Y5H), US(OFF_Y5L), FP(OFF_P3));
  // fc1: [128,9216] x [4096,9216]^T, K split 16 x 576
  fc_mfma_kernel<<<dim3(32, 16), 256, 0, stream>>>(FP(OFF_P3), fc1_w, FP(OFF_PART), 9216, 576, 4096);
  fc_reduce_kernel<<<2048, 256, 0, stream>>>(FP(OFF_PART), fc1_b, FP(OFF_FC1), 4096, 16, 1);
  // fc2: [128,4096] x [4096,4096]^T, K split 16 x 256
  fc_mfma_kernel<<<dim3(32, 16), 256, 0, stream>>>(FP(OFF_FC1), fc2_w, FP(OFF_PART), 4096, 256, 4096);
  fc_reduce_kernel<<<2048, 256, 0, stream>>>(FP(OFF_PART), fc2_b, FP(OFF_FC2), 4096, 16, 1);
  // fc3 + post
  fc3_kernel<<<128, 256, 0, stream>>>(FP(OFF_FC2), fc3_w, fc3_b, FP(OFF_LOG));
  post_kernel<<<1, 128, 0, stream>>>(FP(OFF_LOG), unif, noise, out);
}

// Round 7
// 874.300 us; speedup vs baseline: 14.8796x; 1.0231x over previous
//
#include <hip/hip_runtime.h>
#include <math.h>

// ---------------------------------------------------------------------------
// AlexNet forward, batch 128.
// Round 6: scheduling fixes — explicit weight-prefetch double-buffer and
// product-phase-major MFMA order (same-acc dependency spacing) in
// conv2/conv13/fc; pool1+bf16-convert fused into one pass.
//
// Workspace layout (bytes):
//   X2 hi/lo [0,25.69M)   conv1out fp32 [25.69M,132.15M)  (dead after pool1cvt)
//   wt2/3/4/5 hi/lo [25.69M,35.47M)  (written after conv1out dead)
//   Y2 hi/lo [36M,113.07M)   X3 hi/lo [113.1M,129.71M)
//   Y3 [36M,69.23M)  Y4 [70M,92.15M)  Y5 [93M,115.15M)
//   P3 [0,4.72M)  FC1 [5M,7.1M)  FC2 [8M,10.1M)  LOG [11M)  PART [40M,73.6M)
// ---------------------------------------------------------------------------

typedef __attribute__((ext_vector_type(4))) float  f32x4;
typedef __attribute__((ext_vector_type(8))) short  bf16x8;

#define OFF_C1O      25690112ull
#define OFF_X2H      0ull
#define OFF_X2L      12845056ull
#define OFF_WT2H     25690112ull
#define OFF_WT2L     26304512ull
#define OFF_WT3H     26918912ull
#define OFF_WT3L     28246016ull
#define OFF_WT4H     29573120ull
#define OFF_WT4L     31342592ull
#define OFF_WT5H     33112064ull
#define OFF_WT5L     34291712ull
#define OFF_Y2H      36000000ull
#define OFF_Y2L      74535168ull
#define OFF_X3H      113100000ull
#define OFF_X3L      121406688ull
#define OFF_Y3H      36000000ull
#define OFF_Y3L      52613376ull
#define OFF_Y4H      70000000ull
#define OFF_Y4L      81075584ull
#define OFF_Y5H      93000000ull
#define OFF_Y5L      104075584ull
#define OFF_P3       0ull
#define OFF_FC1      5000000ull
#define OFF_FC2      8000000ull
#define OFF_LOG      11000000ull
#define OFF_PART     40000000ull

__device__ inline void bf16split(float v, unsigned short& h, unsigned short& l) {
  unsigned u = __builtin_bit_cast(unsigned, v);
  unsigned hb = (u + 0x7fffu + ((u >> 16) & 1u)) >> 16;        // RNE to bf16
  h = (unsigned short)hb;
  float hf = __builtin_bit_cast(float, hb << 16);
  float r = v - hf;
  unsigned u2 = __builtin_bit_cast(unsigned, r);
  l = (unsigned short)((u2 + 0x7fffu + ((u2 >> 16) & 1u)) >> 16);
}
// trunc-hi split: hi exact truncation, lo = RNE(v - hi)
__device__ inline void bf16split_fast(float v, unsigned short& h, unsigned short& l) {
  unsigned u = __builtin_bit_cast(unsigned, v);
  h = (unsigned short)(u >> 16);
  float r = v - __builtin_bit_cast(float, u & 0xFFFF0000u);
  unsigned u2 = __builtin_bit_cast(unsigned, r);
  l = (unsigned short)((u2 + 0x7fffu + ((u2 >> 16) & 1u)) >> 16);
}
__device__ inline float bf2f(unsigned short h) {
  return __builtin_bit_cast(float, ((unsigned)h) << 16);
}

// ---------------- conv1: x[128,3,224,224] -> y1[128,64,57,57], k3 s4 p2, relu
__global__ __launch_bounds__(256) void conv1_kernel(
    const float* __restrict__ x, const float* __restrict__ w,
    const float* __restrict__ bias, float* __restrict__ out) {
  const int b = blockIdx.y;
  const int s = blockIdx.x * 256 + threadIdx.x;
  if (s >= 57 * 57) return;
  const int oh = s / 57, ow = s % 57;
  float iv[27];
#pragma unroll
  for (int ci = 0; ci < 3; ++ci)
#pragma unroll
    for (int kh = 0; kh < 3; ++kh)
#pragma unroll
      for (int kw = 0; kw < 3; ++kw) {
        const int ih = oh * 4 - 2 + kh;
        const int iw = ow * 4 - 2 + kw;
        float v = 0.f;
        if (ih >= 0 && ih < 224 && iw >= 0 && iw < 224)
          v = x[(((size_t)b * 3 + ci) * 224 + ih) * 224 + iw];
        iv[ci * 9 + kh * 3 + kw] = v;
      }
  for (int co = 0; co < 64; ++co) {
    float a = bias[co];
#pragma unroll
    for (int p = 0; p < 27; ++p) a = fmaf(w[co * 27 + p], iv[p], a);
    out[((size_t)b * 64 + co) * 3249 + s] = fmaxf(a, 0.f);
  }
}

// ---------------- fused pool1 + bf16 hi/lo convert:
// conv1out fp32 [b][64][57][57] -> X2 hi/lo bf16 [b][784][64]
__global__ __launch_bounds__(256) void pool1cvt_kernel(
    const float* __restrict__ in, unsigned short* __restrict__ xh,
    unsigned short* __restrict__ xl) {
  const int tid = blockIdx.x * 256 + threadIdx.x;
  if (tid >= 128 * 784) return;
  const int b = tid / 784, s = tid % 784;
  const int oh = s / 28, ow = s % 28;
  const float* base = in + (size_t)b * 64 * 3249 + (size_t)(oh * 2) * 57 + ow * 2;
  for (int cg = 0; cg < 16; ++cg) {
    unsigned short h[4], l[4];
#pragma unroll
    for (int j = 0; j < 4; ++j) {
      const float* p = base + (size_t)(cg * 4 + j) * 3249;
      float m = -INFINITY;
#pragma unroll
      for (int kh = 0; kh < 3; ++kh)
#pragma unroll
        for (int kw = 0; kw < 3; ++kw) m = fmaxf(m, p[kh * 57 + kw]);
      bf16split(m, h[j], l[j]);
    }
    const size_t g = ((size_t)b * 784 + s) * 64 + cg * 4;
    *reinterpret_cast<uint2*>(xh + g) =
        make_uint2((unsigned)h[0] | ((unsigned)h[1] << 16),
                   (unsigned)h[2] | ((unsigned)h[3] << 16));
    *reinterpret_cast<uint2*>(xl + g) =
        make_uint2((unsigned)l[0] | ((unsigned)l[1] << 16),
                   (unsigned)l[2] | ((unsigned)l[3] << 16));
  }
}

// ---------------- weight transform: w[co][ci][P] fp32 -> wh/wl [co][p][ci] bf16
__global__ void wtrans_hl_kernel(const float* __restrict__ w,
                                 unsigned short* __restrict__ wh,
                                 unsigned short* __restrict__ wl,
                                 int C_in, int P, int C_out) {
  const int total = C_out * P * C_in;
  for (int e = blockIdx.x * blockDim.x + threadIdx.x; e < total;
       e += gridDim.x * blockDim.x) {
    const int ci = e % C_in;
    const int p = (e / C_in) % P;
    const int co = e / (C_in * P);
    const float v = w[((size_t)co * C_in + ci) * P + p];
    unsigned short h, l;
    bf16split(v, h, l);
    wh[e] = h; wl[e] = l;
  }
}

// ---------------- conv2 MFMA v2: weight dbuf + product-major order
__global__ __launch_bounds__(256, 2) void conv2_mfma_kernel(
    const unsigned short* __restrict__ xh, const unsigned short* __restrict__ xl,
    const unsigned short* __restrict__ wh, const unsigned short* __restrict__ wl,
    const float* __restrict__ bias,
    unsigned short* __restrict__ yh, unsigned short* __restrict__ yl) {
  __shared__ unsigned short xt_h[352 * 40];
  __shared__ unsigned short xt_l[352 * 40];
  const int t = threadIdx.x;
  const int lane = t & 63, wv = t >> 6;
  const int b = blockIdx.x;
  const int rg = blockIdx.y;
  const int cg = blockIdx.z;
  const int fr = lane & 15, fq = lane >> 4;
  const int k0 = fq * 8;

  int bofs[4];
  bool act[4];
#pragma unroll
  for (int ti = 0; ti < 4; ++ti) {
    const int tile = ti * 4 + wv;
    act[ti] = (tile <= 12);
    int n = tile * 16 + fr;
    if (tile > 12 || n > 195) n = 195;
    const int r = n / 28, c = n % 28;
    bofs[ti] = (r * 32 + c) * 40 + k0;
  }

  f32x4 acc[4][4];
#pragma unroll
  for (int i = 0; i < 4; ++i)
#pragma unroll
    for (int j = 0; j < 4; ++j) acc[i][j] = (f32x4){0.f, 0.f, 0.f, 0.f};

  for (int cc = 0; cc < 2; ++cc) {
    __syncthreads();
    for (int e = t; e < 1408; e += 256) {
      const int sp = e >> 2, kg = e & 3;
      const int hr = sp >> 5, hc = sp & 31;
      const int ih = rg * 7 + hr - 2, ic = hc - 2;
      uint4 vh = make_uint4(0, 0, 0, 0), vl = make_uint4(0, 0, 0, 0);
      if (ih >= 0 && ih < 28 && ic >= 0 && ic < 28) {
        const size_t g = ((size_t)b * 784 + ih * 28 + ic) * 64 + cc * 32 + kg * 8;
        vh = *reinterpret_cast<const uint4*>(xh + g);
        vl = *reinterpret_cast<const uint4*>(xl + g);
      }
      *reinterpret_cast<uint4*>(xt_h + sp * 40 + kg * 8) = vh;
      *reinterpret_cast<uint4*>(xt_l + sp * 40 + kg * 8) = vl;
    }
    __syncthreads();

    // prologue: p=0 weights
    bf16x8 cur_h[4], cur_l[4];
#pragma unroll
    for (int cot = 0; cot < 4; ++cot) {
      const size_t wg = ((size_t)(cg * 64 + cot * 16 + fr) * 25) * 64 + cc * 32 + k0;
      cur_h[cot] = __builtin_bit_cast(bf16x8, *reinterpret_cast<const uint4*>(wh + wg));
      cur_l[cot] = __builtin_bit_cast(bf16x8, *reinterpret_cast<const uint4*>(wl + wg));
    }
#pragma unroll 5
    for (int p = 0; p < 25; ++p) {
      bf16x8 nxt_h[4], nxt_l[4];
      if (p < 24) {
#pragma unroll
        for (int cot = 0; cot < 4; ++cot) {
          const size_t wg = ((size_t)(cg * 64 + cot * 16 + fr) * 25 + (p + 1)) * 64 + cc * 32 + k0;
          nxt_h[cot] = __builtin_bit_cast(bf16x8, *reinterpret_cast<const uint4*>(wh + wg));
          nxt_l[cot] = __builtin_bit_cast(bf16x8, *reinterpret_cast<const uint4*>(wl + wg));
        }
      }
      const int kh = p / 5, kw = p % 5;
      const int poff = (kh * 32 + kw) * 40;
      bf16x8 bh[4], bl[4];
#pragma unroll
      for (int ti = 0; ti < 4; ++ti) {
        if (act[ti]) {
          bh[ti] = __builtin_bit_cast(bf16x8,
              *reinterpret_cast<const uint4*>(xt_h + bofs[ti] + poff));
          bl[ti] = __builtin_bit_cast(bf16x8,
              *reinterpret_cast<const uint4*>(xt_l + bofs[ti] + poff));
        }
      }
      // phase hh
#pragma unroll
      for (int ti = 0; ti < 4; ++ti) if (act[ti])
#pragma unroll
        for (int cot = 0; cot < 4; ++cot)
          acc[ti][cot] = __builtin_amdgcn_mfma_f32_16x16x32_bf16(cur_h[cot], bh[ti], acc[ti][cot], 0, 0, 0);
      // phase h*lo_x
#pragma unroll
      for (int ti = 0; ti < 4; ++ti) if (act[ti])
#pragma unroll
        for (int cot = 0; cot < 4; ++cot)
          acc[ti][cot] = __builtin_amdgcn_mfma_f32_16x16x32_bf16(cur_h[cot], bl[ti], acc[ti][cot], 0, 0, 0);
      // phase lo_w*h
#pragma unroll
      for (int ti = 0; ti < 4; ++ti) if (act[ti])
#pragma unroll
        for (int cot = 0; cot < 4; ++cot)
          acc[ti][cot] = __builtin_amdgcn_mfma_f32_16x16x32_bf16(cur_l[cot], bh[ti], acc[ti][cot], 0, 0, 0);
      if (p < 24) {
#pragma unroll
        for (int cot = 0; cot < 4; ++cot) { cur_h[cot] = nxt_h[cot]; cur_l[cot] = nxt_l[cot]; }
      }
    }
  }
#pragma unroll
  for (int cot = 0; cot < 4; ++cot) {
    const int co = cg * 64 + cot * 16 + fq * 4;
    const float4 bi = *reinterpret_cast<const float4*>(bias + co);
    const float bia[4] = {bi.x, bi.y, bi.z, bi.w};
#pragma unroll
    for (int ti = 0; ti < 4; ++ti) {
      const int tile = ti * 4 + wv;
      if (tile > 12) continue;
      const int n = tile * 16 + fr;
      if (n > 195) continue;
      const int oh = rg * 7 + n / 28, ow = n % 28;
      unsigned short h[4], l[4];
#pragma unroll
      for (int r = 0; r < 4; ++r) {
        const float v = fmaxf(acc[ti][cot][r] + bia[r], 0.f);
        bf16split(v, h[r], l[r]);
      }
      const size_t g = ((size_t)b * 784 + oh * 28 + ow) * 192 + co;
      *reinterpret_cast<uint2*>(yh + g) =
          make_uint2((unsigned)h[0] | ((unsigned)h[1] << 16),
                     (unsigned)h[2] | ((unsigned)h[3] << 16));
      *reinterpret_cast<uint2*>(yl + g) =
          make_uint2((unsigned)l[0] | ((unsigned)l[1] << 16),
                     (unsigned)l[2] | ((unsigned)l[3] << 16));
    }
  }
}

// ---------------- pool2: Y2 hi/lo [b][784][192] -> X3 hi/lo [b][169][192]
__global__ __launch_bounds__(192) void pool2_hl_kernel(
    const unsigned short* __restrict__ yh, const unsigned short* __restrict__ yl,
    unsigned short* __restrict__ xh, unsigned short* __restrict__ xl) {
  const int b = blockIdx.x, oh = blockIdx.y;
  const int c = threadIdx.x;
  for (int ow = 0; ow < 13; ++ow) {
    float m = -INFINITY;
#pragma unroll
    for (int kh = 0; kh < 3; ++kh)
#pragma unroll
      for (int kw = 0; kw < 3; ++kw) {
        const int s = (oh * 2 + kh) * 28 + (ow * 2 + kw);
        const size_t g = ((size_t)b * 784 + s) * 192 + c;
        m = fmaxf(m, bf2f(yh[g]) + bf2f(yl[g]));
      }
    unsigned short h, l;
    bf16split(m, h, l);
    const size_t gd = ((size_t)b * 169 + oh * 13 + ow) * 192 + c;
    xh[gd] = h; xl[gd] = l;
  }
}

// ---------------- conv3/4/5 MFMA v2: weight dbuf + quad product-major
__global__ __launch_bounds__(256, 4) void conv13_mfma_kernel(
    const unsigned short* __restrict__ xh, const unsigned short* __restrict__ xl,
    const unsigned short* __restrict__ wh, const unsigned short* __restrict__ wl,
    const float* __restrict__ bias,
    unsigned short* __restrict__ yh, unsigned short* __restrict__ yl,
    int C_in, int C_out) {
  __shared__ unsigned short xt_h[225 * 40];
  __shared__ unsigned short xt_l[225 * 40];
  const int t = threadIdx.x;
  const int lane = t & 63;
  const int wv = t >> 6;
  const int b = blockIdx.x;
  const int co0 = blockIdx.y * 64 + wv * 16;
  const int fr = lane & 15;
  const int fq = lane >> 4;
  const int k0 = fq * 8;

  int bofs[11];
#pragma unroll
  for (int nt = 0; nt < 11; ++nt) {
    int n = nt * 16 + fr;
    if (n > 168) n = 168;
    const int oh = n / 13, ow = n % 13;
    bofs[nt] = (oh * 15 + ow) * 40 + k0;
  }

  f32x4 acc[11];
#pragma unroll
  for (int nt = 0; nt < 11; ++nt) acc[nt] = (f32x4){0.f, 0.f, 0.f, 0.f};

  const size_t wrow = (size_t)(co0 + fr) * 9;
  const int nchunk = C_in >> 5;
  for (int cc = 0; cc < nchunk; ++cc) {
    __syncthreads();
    for (int e = t; e < 900; e += 256) {
      const int sp = e >> 2, kg = e & 3;
      const int r = sp / 15, c = sp % 15;
      const int ir = r - 1, ic = c - 1;
      uint4 vh = make_uint4(0, 0, 0, 0), vl = make_uint4(0, 0, 0, 0);
      if (ir >= 0 && ir < 13 && ic >= 0 && ic < 13) {
        const size_t g = ((size_t)b * 169 + ir * 13 + ic) * C_in + cc * 32 + kg * 8;
        vh = *reinterpret_cast<const uint4*>(xh + g);
        vl = *reinterpret_cast<const uint4*>(xl + g);
      }
      *reinterpret_cast<uint4*>(xt_h + sp * 40 + kg * 8) = vh;
      *reinterpret_cast<uint4*>(xt_l + sp * 40 + kg * 8) = vl;
    }
    __syncthreads();
    const int cbase = cc * 32 + k0;
    bf16x8 ca_h = __builtin_bit_cast(bf16x8, *reinterpret_cast<const uint4*>(wh + wrow * C_in + cbase));
    bf16x8 ca_l = __builtin_bit_cast(bf16x8, *reinterpret_cast<const uint4*>(wl + wrow * C_in + cbase));
#pragma unroll
    for (int p = 0; p < 9; ++p) {
      bf16x8 na_h, na_l;
      if (p < 8) {
        na_h = __builtin_bit_cast(bf16x8, *reinterpret_cast<const uint4*>(wh + (wrow + p + 1) * C_in + cbase));
        na_l = __builtin_bit_cast(bf16x8, *reinterpret_cast<const uint4*>(wl + (wrow + p + 1) * C_in + cbase));
      }
      const int poff = ((p / 3) * 15 + (p % 3)) * 40;
#pragma unroll
      for (int q = 0; q < 3; ++q) {
        const int nq = (q < 2) ? 4 : 3;
        bf16x8 bh[4], bl[4];
#pragma unroll
        for (int i = 0; i < 4; ++i) {
          if (i < nq) {
            bh[i] = __builtin_bit_cast(bf16x8,
                *reinterpret_cast<const uint4*>(xt_h + bofs[q * 4 + i] + poff));
            bl[i] = __builtin_bit_cast(bf16x8,
                *reinterpret_cast<const uint4*>(xt_l + bofs[q * 4 + i] + poff));
          }
        }
#pragma unroll
        for (int i = 0; i < 4; ++i) if (i < nq)
          acc[q * 4 + i] = __builtin_amdgcn_mfma_f32_16x16x32_bf16(ca_h, bh[i], acc[q * 4 + i], 0, 0, 0);
#pragma unroll
        for (int i = 0; i < 4; ++i) if (i < nq)
          acc[q * 4 + i] = __builtin_amdgcn_mfma_f32_16x16x32_bf16(ca_h, bl[i], acc[q * 4 + i], 0, 0, 0);
#pragma unroll
        for (int i = 0; i < 4; ++i) if (i < nq)
          acc[q * 4 + i] = __builtin_amdgcn_mfma_f32_16x16x32_bf16(ca_l, bh[i], acc[q * 4 + i], 0, 0, 0);
      }
      if (p < 8) { ca_h = na_h; ca_l = na_l; }
    }
  }
  const int co_w = co0 + fq * 4;
  const float4 bi = *reinterpret_cast<const float4*>(bias + co_w);
  const float bia[4] = {bi.x, bi.y, bi.z, bi.w};
#pragma unroll
  for (int nt = 0; nt < 11; ++nt) {
    const int n = nt * 16 + fr;
    if (n > 168) continue;
    unsigned short h[4], l[4];
#pragma unroll
    for (int r = 0; r < 4; ++r) {
      float v = fmaxf(acc[nt][r] + bia[r], 0.f);
      bf16split(v, h[r], l[r]);
    }
    const size_t g = ((size_t)b * 169 + n) * C_out + co_w;
    *reinterpret_cast<uint2*>(yh + g) =
        make_uint2((unsigned)h[0] | ((unsigned)h[1] << 16),
                   (unsigned)h[2] | ((unsigned)h[3] << 16));
    *reinterpret_cast<uint2*>(yl + g) =
        make_uint2((unsigned)l[0] | ((unsigned)l[1] << 16),
                   (unsigned)l[2] | ((unsigned)l[3] << 16));
  }
}

// ---------------- pool3: Y5 hi/lo [b][169][256] -> fp32 [b][256][6][6]
__global__ __launch_bounds__(256) void pool3_hl_kernel(
    const unsigned short* __restrict__ yh, const unsigned short* __restrict__ yl,
    float* __restrict__ out) {
  const int b = blockIdx.x;
  const int s2 = blockIdx.y;
  const int c = threadIdx.x;
  const int oh = s2 / 6, ow = s2 % 6;
  float m = -INFINITY;
#pragma unroll
  for (int kh = 0; kh < 3; ++kh)
#pragma unroll
    for (int kw = 0; kw < 3; ++kw) {
      const int si = (oh * 2 + kh) * 13 + (ow * 2 + kw);
      const size_t g = ((size_t)b * 169 + si) * 256 + c;
      m = fmaxf(m, bf2f(yh[g]) + bf2f(yl[g]));
    }
  out[((size_t)b * 256 + c) * 36 + s2] = m;
}

// ---------------- fc1/fc2 MFMA: reg-split weights, nt-pair product-major
__global__ __launch_bounds__(256, 2) void fc_mfma_kernel(
    const float* __restrict__ act, const float* __restrict__ Wm,
    float* __restrict__ part, int K, int kchunk, int Cout) {
  __shared__ unsigned short ah[128 * 40];
  __shared__ unsigned short al[128 * 40];
  const int t = threadIdx.x;
  const int lane = t & 63, wv = t >> 6;
  const int m0 = blockIdx.x * 128 + wv * 32;
  const int kb = blockIdx.y * kchunk;
  const int fr = lane & 15, fq = lane >> 4;

  f32x4 acc[2][8];
#pragma unroll
  for (int i = 0; i < 2; ++i)
#pragma unroll
    for (int j = 0; j < 8; ++j) acc[i][j] = (f32x4){0.f, 0.f, 0.f, 0.f};

  for (int kc = kb; kc < kb + kchunk; kc += 32) {
    __syncthreads();
#pragma unroll
    for (int i = 0; i < 4; ++i) {
      const int u = t + i * 256;
      const int n = u >> 3, j = u & 7;
      const float4 v = *reinterpret_cast<const float4*>(act + (size_t)n * K + kc + j * 4);
      const float vv[4] = {v.x, v.y, v.z, v.w};
      unsigned short h[4], l[4];
#pragma unroll
      for (int q = 0; q < 4; ++q) bf16split_fast(vv[q], h[q], l[q]);
      *reinterpret_cast<uint2*>(ah + n * 40 + j * 4) =
          make_uint2((unsigned)h[0] | ((unsigned)h[1] << 16),
                     (unsigned)h[2] | ((unsigned)h[3] << 16));
      *reinterpret_cast<uint2*>(al + n * 40 + j * 4) =
          make_uint2((unsigned)l[0] | ((unsigned)l[1] << 16),
                     (unsigned)l[2] | ((unsigned)l[3] << 16));
    }
    __syncthreads();
    bf16x8 a_h[2], a_l[2];
#pragma unroll
    for (int mt = 0; mt < 2; ++mt) {
      const float* wp = Wm + (size_t)(m0 + mt * 16 + fr) * K + kc + fq * 8;
      const float4 w0 = *reinterpret_cast<const float4*>(wp);
      const float4 w1 = *reinterpret_cast<const float4*>(wp + 4);
      const float ws[8] = {w0.x, w0.y, w0.z, w0.w, w1.x, w1.y, w1.z, w1.w};
#pragma unroll
      for (int q = 0; q < 8; ++q) {
        unsigned short h, l;
        bf16split_fast(ws[q], h, l);
        a_h[mt][q] = (short)h;
        a_l[mt][q] = (short)l;
      }
    }
#pragma unroll
    for (int np = 0; np < 4; ++np) {
      bf16x8 bh[2], bl[2];
#pragma unroll
      for (int i = 0; i < 2; ++i) {
        const int nt = np * 2 + i;
        bh[i] = __builtin_bit_cast(bf16x8,
            *reinterpret_cast<const uint4*>(ah + (nt * 16 + fr) * 40 + fq * 8));
        bl[i] = __builtin_bit_cast(bf16x8,
            *reinterpret_cast<const uint4*>(al + (nt * 16 + fr) * 40 + fq * 8));
      }
#pragma unroll
      for (int i = 0; i < 2; ++i)
#pragma unroll
        for (int mt = 0; mt < 2; ++mt)
          acc[mt][np * 2 + i] = __builtin_amdgcn_mfma_f32_16x16x32_bf16(a_h[mt], bh[i], acc[mt][np * 2 + i], 0, 0, 0);
#pragma unroll
      for (int i = 0; i < 2; ++i)
#pragma unroll
        for (int mt = 0; mt < 2; ++mt)
          acc[mt][np * 2 + i] = __builtin_amdgcn_mfma_f32_16x16x32_bf16(a_h[mt], bl[i], acc[mt][np * 2 + i], 0, 0, 0);
#pragma unroll
      for (int i = 0; i < 2; ++i)
#pragma unroll
        for (int mt = 0; mt < 2; ++mt)
          acc[mt][np * 2 + i] = __builtin_amdgcn_mfma_f32_16x16x32_bf16(a_l[mt], bh[i], acc[mt][np * 2 + i], 0, 0, 0);
    }
  }
  const size_t base = (size_t)blockIdx.y * Cout * 128;
#pragma unroll
  for (int mt = 0; mt < 2; ++mt) {
#pragma unroll
    for (int nt = 0; nt < 8; ++nt) {
#pragma unroll
      for (int r = 0; r < 4; ++r) {
        const int m = m0 + mt * 16 + fq * 4 + r;
        const int n = nt * 16 + fr;
        part[base + (size_t)m * 128 + n] = acc[mt][nt][r];
      }
    }
  }
}

// ---------------- fc reduce: sum KS partials, +bias, relu, transpose to [n][Cout]
__global__ __launch_bounds__(256) void fc_reduce_kernel(
    const float* __restrict__ part, const float* __restrict__ bias,
    float* __restrict__ out, int Cout, int KS, int relu) {
  const int g = blockIdx.x * 256 + threadIdx.x;
  if (g >= Cout * 128) return;
  const int n = g & 127, m = g >> 7;
  float s = 0.f;
  for (int ks = 0; ks < KS; ++ks)
    s += part[(size_t)ks * Cout * 128 + (size_t)m * 128 + n];
  s += bias[m];
  if (relu) s = fmaxf(s, 0.f);
  out[(size_t)n * Cout + m] = s;
}

// ---------------- fc3: logits[128,10]
__global__ __launch_bounds__(256) void fc3_kernel(
    const float* __restrict__ A, const float* __restrict__ W,
    const float* __restrict__ bias, float* __restrict__ out) {
  __shared__ float red[256];
  const int b = blockIdx.x;
  const int t = threadIdx.x;
  float acc[10];
#pragma unroll
  for (int n = 0; n < 10; ++n) acc[n] = 0.f;
  const float* a = A + (size_t)b * 4096;
  for (int k = t; k < 4096; k += 256) {
    const float av = a[k];
#pragma unroll
    for (int n = 0; n < 10; ++n) acc[n] = fmaf(av, W[n * 4096 + k], acc[n]);
  }
  for (int n = 0; n < 10; ++n) {
    red[t] = acc[n];
    __syncthreads();
    for (int off = 128; off > 0; off >>= 1) {
      if (t < off) red[t] += red[t + off];
      __syncthreads();
    }
    if (t == 0) out[b * 10 + n] = red[0] + bias[n];
    __syncthreads();
  }
}

// ---------------- post
__global__ void post_kernel(const float* __restrict__ logits,
                            const float* __restrict__ unif,
                            const float* __restrict__ noise,
                            float* __restrict__ out) {
  const int b = blockIdx.x * blockDim.x + threadIdx.x;
  if (b >= 128) return;
  float lg[10];
#pragma unroll
  for (int j = 0; j < 10; ++j) lg[j] = logits[b * 10 + j];
  float m = lg[0];
  int idx = 0;
#pragma unroll
  for (int j = 1; j < 10; ++j) {
    if (lg[j] > m) { m = lg[j]; idx = j; }
  }
  float v[10];
#pragma unroll
  for (int j = 0; j < 10; ++j)
    v[j] = ((j == idx) ? lg[j] : unif[b * 10 + j] * m) + noise[b * 10 + j];
  float mx = v[0];
#pragma unroll
  for (int j = 1; j < 10; ++j) mx = fmaxf(mx, v[j]);
  float sum = 0.f;
#pragma unroll
  for (int j = 0; j < 10; ++j) { v[j] = expf(v[j] - mx); sum += v[j]; }
  const float inv = 1.f / sum;
#pragma unroll
  for (int j = 0; j < 10; ++j) out[b * 10 + j] = v[j] * inv;
}

// ---------------------------------------------------------------------------
extern "C" void kernel_launch(void* const* d_in, const int* in_sizes, int n_in,
                              void* d_out, int out_size, void* d_ws, size_t ws_size,
                              hipStream_t stream) {
  const float* x     = (const float*)d_in[0];
  const float* w1    = (const float*)d_in[1];
  const float* b1    = (const float*)d_in[2];
  const float* w2    = (const float*)d_in[3];
  const float* b2    = (const float*)d_in[4];
  const float* w3    = (const float*)d_in[5];
  const float* b3    = (const float*)d_in[6];
  const float* w4    = (const float*)d_in[7];
  const float* b4    = (const float*)d_in[8];
  const float* w5    = (const float*)d_in[9];
  const float* b5    = (const float*)d_in[10];
  const float* fc1_w = (const float*)d_in[11];
  const float* fc1_b = (const float*)d_in[12];
  const float* fc2_w = (const float*)d_in[13];
  const float* fc2_b = (const float*)d_in[14];
  const float* fc3_w = (const float*)d_in[15];
  const float* fc3_b = (const float*)d_in[16];
  const float* unif  = (const float*)d_in[17];
  const float* noise = (const float*)d_in[18];
  float* out = (float*)d_out;

  char* W = (char*)d_ws;
#define FP(off) ((float*)(W + (off)))
#define US(off) ((unsigned short*)(W + (off)))

  // conv1 -> fp32 [128,64,57,57] at OFF_C1O
  conv1_kernel<<<dim3(13, 128), 256, 0, stream>>>(x, w1, b1, FP(OFF_C1O));
  // fused pool1+convert -> X2 hi/lo [b][784][64]  (conv1out dead after)
  pool1cvt_kernel<<<392, 256, 0, stream>>>(FP(OFF_C1O), US(OFF_X2H), US(OFF_X2L));
  // weight transforms (overwrite conv1out head — dead)
  wtrans_hl_kernel<<<512, 256, 0, stream>>>(w2, US(OFF_WT2H), US(OFF_WT2L), 64, 25, 192);
  wtrans_hl_kernel<<<512, 256, 0, stream>>>(w3, US(OFF_WT3H), US(OFF_WT3L), 192, 9, 384);
  wtrans_hl_kernel<<<512, 256, 0, stream>>>(w4, US(OFF_WT4H), US(OFF_WT4L), 384, 9, 256);
  wtrans_hl_kernel<<<512, 256, 0, stream>>>(w5, US(OFF_WT5H), US(OFF_WT5L), 256, 9, 256);
  // conv2 -> Y2 hi/lo [b][784][192]
  conv2_mfma_kernel<<<dim3(128, 4, 3), 256, 0, stream>>>(
      US(OFF_X2H), US(OFF_X2L), US(OFF_WT2H), US(OFF_WT2L), b2,
      US(OFF_Y2H), US(OFF_Y2L));
  // pool2 -> X3 hi/lo [b][169][192]
  pool2_hl_kernel<<<dim3(128, 13), 192, 0, stream>>>(
      US(OFF_Y2H), US(OFF_Y2L), US(OFF_X3H), US(OFF_X3L));
  // conv3 -> Y3 [b][169][384]
  conv13_mfma_kernel<<<dim3(128, 6), 256, 0, stream>>>(
      US(OFF_X3H), US(OFF_X3L), US(OFF_WT3H), US(OFF_WT3L), b3,
      US(OFF_Y3H), US(OFF_Y3L), 192, 384);
  // conv4 -> Y4 [b][169][256]
  conv13_mfma_kernel<<<dim3(128, 4), 256, 0, stream>>>(
      US(OFF_Y3H), US(OFF_Y3L), US(OFF_WT4H), US(OFF_WT4L), b4,
      US(OFF_Y4H), US(OFF_Y4L), 384, 256);
  // conv5 -> Y5 [b][169][256]
  conv13_mfma_kernel<<<dim3(128, 4), 256, 0, stream>>>(
      US(OFF_Y4H), US(OFF_Y4L), US(OFF_WT5H), US(OFF_WT5L), b5,
      US(OFF_Y5H), US(OFF_Y5L), 256, 256);
  // pool3 -> P3 fp32 [128][9216]
  pool3_hl_kernel<<<dim3(128, 36), 256, 0, stream>>>(US(OFF_Y5H), US(OFF_Y5L), FP(OFF_P3));
  // fc1/fc2
  fc_mfma_kernel<<<dim3(32, 16), 256, 0, stream>>>(FP(OFF_P3), fc1_w, FP(OFF_PART), 9216, 576, 4096);
  fc_reduce_kernel<<<2048, 256, 0, stream>>>(FP(OFF_PART), fc1_b, FP(OFF_FC1), 4096, 16, 1);
  fc_mfma_kernel<<<dim3(32, 16), 256, 0, stream>>>(FP(OFF_FC1), fc2_w, FP(OFF_PART), 4096, 256, 4096);
  fc_reduce_kernel<<<2048, 256, 0, stream>>>(FP(OFF_PART), fc2_b, FP(OFF_FC2), 4096, 16, 1);
  // fc3 + post
  fc3_kernel<<<128, 256, 0, stream>>>(FP(OFF_FC2), fc3_w, fc3_b, FP(OFF_LOG));
  post_kernel<<<1, 128, 0, stream>>>(FP(OFF_LOG), unif, noise, out);
}